// Round 5
// baseline (653.807 us; speedup 1.0000x reference)
//
#include <hip/hip_runtime.h>
#include <math.h>

#define SB 32          // samples per block (8 per wave)
#define NTHREADS 256   // 4 waves

typedef short short8 __attribute__((ext_vector_type(8)));
typedef float f32x4  __attribute__((ext_vector_type(4)));

__device__ __forceinline__ unsigned short f2bf(float f) {
    unsigned int u = __builtin_bit_cast(unsigned int, f);
    unsigned int r = (u + 0x7FFFu + ((u >> 16) & 1u)) >> 16;   // RNE
    return (unsigned short)r;
}
__device__ __forceinline__ float bf2f(unsigned short h) {
    unsigned int u = ((unsigned int)h) << 16;
    return __builtin_bit_cast(float, u);
}
__device__ __forceinline__ unsigned pack2(unsigned short lo, unsigned short hi) {
    return (unsigned)lo | ((unsigned)hi << 16);
}
__device__ __forceinline__ float softplus_f(float z) {
    return z > 15.f ? z : log1pf(expf(z));
}

// ---------------- prep: pack W1 (split hi/lo) + W0 + head weights ----------------
// wB layout (short8 slots): nt*1024 + [hi: ks*64+l | lo: 512+ks*64+l]
// slot element i: B[k][n], k = ks*32 + (l>>4)*8 + i, n = nt*16 + (l&15)
__global__ void prep(const float* __restrict__ W1, const float* __restrict__ W0,
                     const float* __restrict__ Wd, const float* __restrict__ Wo,
                     const float* __restrict__ Wv,
                     unsigned short* __restrict__ wB,
                     float4* __restrict__ w0p, float4* __restrict__ hwp)
{
    int idx = blockIdx.x * blockDim.x + threadIdx.x;
    if (idx < 256) {
        w0p[idx] = make_float4(W0[idx], W0[256 + idx], W0[512 + idx], W0[768 + idx]);
        hwp[idx] = make_float4(Wd[2 * idx], Wd[2 * idx + 1], Wo[idx], Wv[idx]);
    }
    if (idx < 8192) {
        const int l  = idx & 63;
        const int ks = (idx >> 6) & 7;
        const int nt = idx >> 9;
        const int k0 = ks * 32 + (l >> 4) * 8;
        const int n  = nt * 16 + (l & 15);
        const int hbase = (nt * 1024 + ks * 64 + l) * 8;
        const int lbase = (nt * 1024 + 512 + ks * 64 + l) * 8;
        #pragma unroll
        for (int i = 0; i < 8; ++i) {
            const float f = W1[(k0 + i) * 256 + n];
            const unsigned short hi = f2bf(f);
            const unsigned short lo = f2bf(f - bf2f(hi));
            wB[hbase + i] = hi;
            wB[lbase + i] = lo;
        }
    }
}

// A-fragment convention per wave (8 samples), built fully in registers:
//   aF0 rows 0-7: h_hi(sample=row), rows 8-15: h_lo(sample=row-8)
//   aF1 rows 0-7: ta_hi,            rows 8-15: tb_hi
//   aF2 rows 0-7: ta_lo,            rows 8-15: tb_lo
// Lane l holds A[row=l&15][k = ks*32 + (l>>4)*8 + i]; lanes l and l+8 redundantly
// compute the same sample's activations (one keeps hi, one keeps lo).
__global__ __launch_bounds__(NTHREADS, 2)
void lode_mfma(const float* __restrict__ x,
               const float4* __restrict__ w0p, const float* __restrict__ b0,
               const unsigned short* __restrict__ wB,
               const float* __restrict__ b1,
               const float4* __restrict__ hwp,
               const float* __restrict__ bd, const float* __restrict__ bo,
               float* __restrict__ out, int n)
{
    const int tid  = threadIdx.x;
    const int wave = tid >> 6;
    const int lane = tid & 63;
    const int r15  = lane & 15;
    const int sLoc = r15 & 7;
    const bool isLo = (r15 >= 8);
    const int kg   = lane >> 4;

    // ---------------- phase 1: in-register A fragments (libm math) ----------------
    int sg1 = blockIdx.x * SB + wave * 8 + sLoc;
    if (sg1 >= n) sg1 = n - 1;
    const float q0 = x[sg1 * 6 + 0];
    const float q1 = x[sg1 * 6 + 1];
    float sn0, cs0, sn1, cs1;
    sincosf(q0, &sn0, &cs0);
    sincosf(q1, &sn1, &cs1);
    const float sA = isLo ? sn1 : sn0;
    const float cA = isLo ? cs1 : cs0;

    short8 aF0[8], aF1[8], aF2[8];
    #pragma unroll
    for (int ks = 0; ks < 8; ++ks) {
        unsigned wH[4], wT[4], wL[4];
        #pragma unroll
        for (int p = 0; p < 4; ++p) {
            const int j0 = ks * 32 + kg * 8 + 2 * p;
            const float4 wa = w0p[j0];
            const float4 wb = w0p[j0 + 1];
            const float2 bb = *reinterpret_cast<const float2*>(&b0[j0]);
            float z0 = bb.x;
            z0 = fmaf(cs0, wa.x, z0); z0 = fmaf(cs1, wa.y, z0);
            z0 = fmaf(sn0, wa.z, z0); z0 = fmaf(sn1, wa.w, z0);
            float z1 = bb.y;
            z1 = fmaf(cs0, wb.x, z1); z1 = fmaf(cs1, wb.y, z1);
            z1 = fmaf(sn0, wb.z, z1); z1 = fmaf(sn1, wb.w, z1);
            const float h0 = tanhf(z0);
            const float h1 = tanhf(z1);
            const unsigned short h0h = f2bf(h0);
            const unsigned short h1h = f2bf(h1);
            const unsigned short h0l = f2bf(h0 - bf2f(h0h));
            const unsigned short h1l = f2bf(h1 - bf2f(h1h));
            const float dt0 = fmaf(-h0, h0, 1.f);
            const float dt1 = fmaf(-h1, h1, 1.f);
            const float wx0 = isLo ? wa.y : wa.x, wz0 = isLo ? wa.w : wa.z;
            const float wx1 = isLo ? wb.y : wb.x, wz1 = isLo ? wb.w : wb.z;
            const float t0 = dt0 * fmaf(-sA, wx0, cA * wz0);
            const float t1 = dt1 * fmaf(-sA, wx1, cA * wz1);
            const unsigned short t0h = f2bf(t0);
            const unsigned short t1h = f2bf(t1);
            const unsigned short t0l = f2bf(t0 - bf2f(t0h));
            const unsigned short t1l = f2bf(t1 - bf2f(t1h));
            wH[p] = isLo ? pack2(h0l, h1l) : pack2(h0h, h1h);
            wT[p] = pack2(t0h, t1h);
            wL[p] = pack2(t0l, t1l);
        }
        aF0[ks] = __builtin_bit_cast(short8, make_uint4(wH[0], wH[1], wH[2], wH[3]));
        aF1[ks] = __builtin_bit_cast(short8, make_uint4(wT[0], wT[1], wT[2], wT[3]));
        aF2[ks] = __builtin_bit_cast(short8, make_uint4(wL[0], wL[1], wL[2], wL[3]));
    }

    // ---------------- phase 2: MFMA GEMM, B via plain register loads ----------------
    const short8* __restrict__ W8 = reinterpret_cast<const short8*>(wB);

    float ph0[4] = {0,0,0,0}, ph1[4] = {0,0,0,0}, pho[4] = {0,0,0,0};
    float pt0[4] = {0,0,0,0}, pt1[4] = {0,0,0,0}, pto[4] = {0,0,0,0}, ptv[4] = {0,0,0,0};
    const int col = lane & 15;

    #pragma unroll 1
    for (int nt = 0; nt < 16; ++nt) {
        const int base = nt * 1024 + lane;
        const int ncol = nt * 16 + col;
        const float4 hw  = hwp[ncol];
        const float  b1v = b1[ncol];

        short8 bh[8], bl[8];
        #pragma unroll
        for (int ks = 0; ks < 8; ++ks) {
            bh[ks] = W8[base + ks * 64];
            bl[ks] = W8[base + 512 + ks * 64];
        }

        f32x4 c1a = {0.f,0.f,0.f,0.f};   // {h_hi,h_lo} x W_hi
        f32x4 c2  = {0.f,0.f,0.f,0.f};   // {h_hi,h_lo} x W_lo
        f32x4 c3  = {0.f,0.f,0.f,0.f};   // {ta_hi,tb_hi} x W_hi
        f32x4 c4  = {0.f,0.f,0.f,0.f};   // {ta_hi,tb_hi} x W_lo
        f32x4 c5  = {0.f,0.f,0.f,0.f};   // {ta_lo,tb_lo} x W_hi
        #pragma unroll
        for (int ks = 0; ks < 8; ++ks) {
            c1a = __builtin_amdgcn_mfma_f32_16x16x32_bf16(aF0[ks], bh[ks], c1a, 0, 0, 0);
            c2  = __builtin_amdgcn_mfma_f32_16x16x32_bf16(aF0[ks], bl[ks], c2,  0, 0, 0);
            c3  = __builtin_amdgcn_mfma_f32_16x16x32_bf16(aF1[ks], bh[ks], c3,  0, 0, 0);
            c4  = __builtin_amdgcn_mfma_f32_16x16x32_bf16(aF1[ks], bl[ks], c4,  0, 0, 0);
            c5  = __builtin_amdgcn_mfma_f32_16x16x32_bf16(aF2[ks], bh[ks], c5,  0, 0, 0);
        }

        // epilogue: lanes<32 = rows 0-7 (h_hi part / ta); lanes>=32 = rows 8-15 (h_lo / tb)
        #pragma unroll
        for (int r = 0; r < 4; ++r) {
            const float zs = c1a[r] + c2[r];
            const float zp = __shfl_xor(zs, 32);
            const float z  = zs + zp + b1v;
            const float h1 = tanhf(z);
            const float dt = fmaf(-h1, h1, 1.f);
            const float tt = c3[r] + c4[r] + c5[r];
            const float t1 = dt * tt;                 // ta lanes<32, tb lanes>=32
            ph0[r] = fmaf(h1, hw.x, ph0[r]);
            ph1[r] = fmaf(h1, hw.y, ph1[r]);
            pho[r] = fmaf(h1, hw.z, pho[r]);
            pt0[r] = fmaf(t1, hw.x, pt0[r]);
            pt1[r] = fmaf(t1, hw.y, pt1[r]);
            pto[r] = fmaf(t1, hw.z, pto[r]);
            ptv[r] = fmaf(t1, hw.w, ptv[r]);
        }
    }

    // ---------------- column reduction across 16 lanes ----------------
    #pragma unroll
    for (int r = 0; r < 4; ++r) {
        #pragma unroll
        for (int m = 1; m < 16; m <<= 1) {
            ph0[r] += __shfl_xor(ph0[r], m);
            ph1[r] += __shfl_xor(ph1[r], m);
            pho[r] += __shfl_xor(pho[r], m);
            pt0[r] += __shfl_xor(pt0[r], m);
            pt1[r] += __shfl_xor(pt1[r], m);
            pto[r] += __shfl_xor(pto[r], m);
            ptv[r] += __shfl_xor(ptv[r], m);
        }
    }
    float qt0[4], qt1[4], qto[4], qtv[4];
    #pragma unroll
    for (int r = 0; r < 4; ++r) {
        qt0[r] = __shfl_xor(pt0[r], 32);
        qt1[r] = __shfl_xor(pt1[r], 32);
        qto[r] = __shfl_xor(pto[r], 32);
        qtv[r] = __shfl_xor(ptv[r], 32);
    }

    if (lane < 32 && (lane & 15) == 0) {
        const float bd0 = bd[0], bd1 = bd[1], bo0 = bo[0];
        #pragma unroll
        for (int r = 0; r < 4; ++r) {
            const int s  = ((lane >> 4) << 2) + r;
            const int sg = blockIdx.x * SB + wave * 8 + s;
            if (sg < n) {
                const float u    = x[sg * 6 + 2];
                const float vv   = x[sg * 6 + 3];
                const float tau0 = x[sg * 6 + 4];
                const float tau1 = x[sg * 6 + 5];

                const float zd0 = ph0[r] + bd0;
                const float zd1 = ph1[r] + bd1;
                const float zo  = pho[r] + bo0;

                const float ld0 = softplus_f(zd0) + 1e-4f;
                const float ld1 = softplus_f(zd1) + 1e-4f;
                const float lo  = zo;

                const float sg0 = 1.f / (1.f + expf(-zd0));
                const float sg1 = 1.f / (1.f + expf(-zd1));

                const float pa_d0 = pt0[r], pa_d1 = pt1[r], pa_o = pto[r], pa_v = ptv[r];
                const float pb_d0 = qt0[r], pb_d1 = qt1[r], pb_o = qto[r], pb_v = qtv[r];

                const float ld0a = sg0 * pa_d0, ld0b = sg0 * pb_d0;
                const float ld1a = sg1 * pa_d1, ld1b = sg1 * pb_d1;
                const float loa  = pa_o,        lob  = pb_o;
                const float ga   = pa_v,        gb   = pb_v;

                const float H00 = fmaf(ld0, ld0, 1e-4f);
                const float H01 = ld0 * lo;
                const float H11 = fmaf(lo, lo, fmaf(ld1, ld1, 1e-4f));

                const float dH00a = 2.f * ld0 * ld0a, dH00b = 2.f * ld0 * ld0b;
                const float dH01a = fmaf(ld0a, lo, ld0 * loa);
                const float dH01b = fmaf(ld0b, lo, ld0 * lob);
                const float dH11a = 2.f * fmaf(lo, loa, ld1 * ld1a);
                const float dH11b = 2.f * fmaf(lo, lob, ld1 * ld1b);

                const float wa0 = fmaf(dH00a, u, dH01a * vv);
                const float wa1 = fmaf(dH01a, u, dH11a * vv);
                const float wb0 = fmaf(dH00b, u, dH01b * vv);
                const float wb1 = fmaf(dH01b, u, dH11b * vv);

                const float QFa = dH00a*u*u + 2.f*dH01a*u*vv + dH11a*vv*vv;
                const float QFb = dH00b*u*u + 2.f*dH01b*u*vv + dH11b*vv*vv;

                const float C0 = fmaf(wa0, u, wb0 * vv) - 0.5f * QFa;
                const float C1 = fmaf(wa1, u, wb1 * vv) - 0.5f * QFb;

                const float r0 = tau0 - C0 - ga;
                const float r1 = tau1 - C1 - gb;

                const float det = fmaf(H00, H11, -H01 * H01);
                const float inv = 1.f / det;
                const float qdd0 = (H11 * r0 - H01 * r1) * inv;
                const float qdd1 = (H00 * r1 - H01 * r0) * inv;

                out[sg * 6 + 0] = u;
                out[sg * 6 + 1] = vv;
                out[sg * 6 + 2] = qdd0;
                out[sg * 6 + 3] = qdd1;
                out[sg * 6 + 4] = 0.f;
                out[sg * 6 + 5] = 0.f;
            }
        }
    }
}

extern "C" void kernel_launch(void* const* d_in, const int* in_sizes, int n_in,
                              void* d_out, int out_size, void* d_ws, size_t ws_size,
                              hipStream_t stream) {
    // dict order: t, x, W0, b0, W1, b1, Wd, bd, Wo, bo, Wv, bv
    const float* x  = (const float*)d_in[1];
    const float* W0 = (const float*)d_in[2];
    const float* b0 = (const float*)d_in[3];
    const float* W1 = (const float*)d_in[4];
    const float* b1 = (const float*)d_in[5];
    const float* Wd = (const float*)d_in[6];
    const float* bd = (const float*)d_in[7];
    const float* Wo = (const float*)d_in[8];
    const float* bo = (const float*)d_in[9];
    const float* Wv = (const float*)d_in[10];
    float* out = (float*)d_out;

    unsigned short* wB = (unsigned short*)d_ws;                         // 256 KB
    float4* w0p = (float4*)((char*)d_ws + 262144);                      // 4 KB
    float4* hwp = (float4*)((char*)d_ws + 262144 + 4096);               // 4 KB

    const int n = in_sizes[1] / 6;

    prep<<<32, 256, 0, stream>>>(W1, W0, Wd, Wo, Wv, wB, w0p, hwp);

    const int grid = (n + SB - 1) / SB;
    lode_mfma<<<grid, NTHREADS, 0, stream>>>(x, w0p, b0, wB, b1, hwp, bd, bo, out, n);
}

// Round 6
// 556.960 us; speedup vs baseline: 1.1739x; 1.1739x over previous
//
#include <hip/hip_runtime.h>
#include <math.h>

#define SB 32          // samples per block (8 per wave)
#define NTHREADS 256   // 4 waves

typedef short short8 __attribute__((ext_vector_type(8)));
typedef float f32x4  __attribute__((ext_vector_type(4)));

__device__ __forceinline__ unsigned short f2bf(float f) {
    unsigned int u = __builtin_bit_cast(unsigned int, f);
    unsigned int r = (u + 0x7FFFu + ((u >> 16) & 1u)) >> 16;   // RNE
    return (unsigned short)r;
}
__device__ __forceinline__ float bf2f(unsigned short h) {
    unsigned int u = ((unsigned int)h) << 16;
    return __builtin_bit_cast(float, u);
}
__device__ __forceinline__ unsigned pack2(unsigned short lo, unsigned short hi) {
    return (unsigned)lo | ((unsigned)hi << 16);
}
__device__ __forceinline__ float softplus_f(float z) {
    return z > 15.f ? z : log1pf(expf(z));
}

// ---------------- prep: pack W1 (split hi/lo) + W0 + head weights ----------------
// wB layout (short8 slots): nt*1024 + [hi: ks*64+l | lo: 512+ks*64+l]
// slot element i: B[k][n], k = ks*32 + (l>>4)*8 + i, n = nt*16 + (l&15)
__global__ void prep(const float* __restrict__ W1, const float* __restrict__ W0,
                     const float* __restrict__ Wd, const float* __restrict__ Wo,
                     const float* __restrict__ Wv,
                     unsigned short* __restrict__ wB,
                     float4* __restrict__ w0p, float4* __restrict__ hwp)
{
    int idx = blockIdx.x * blockDim.x + threadIdx.x;
    if (idx < 256) {
        w0p[idx] = make_float4(W0[idx], W0[256 + idx], W0[512 + idx], W0[768 + idx]);
        hwp[idx] = make_float4(Wd[2 * idx], Wd[2 * idx + 1], Wo[idx], Wv[idx]);
    }
    if (idx < 8192) {
        const int l  = idx & 63;
        const int ks = (idx >> 6) & 7;
        const int nt = idx >> 9;
        const int k0 = ks * 32 + (l >> 4) * 8;
        const int n  = nt * 16 + (l & 15);
        const int hbase = (nt * 1024 + ks * 64 + l) * 8;
        const int lbase = (nt * 1024 + 512 + ks * 64 + l) * 8;
        #pragma unroll
        for (int i = 0; i < 8; ++i) {
            const float f = W1[(k0 + i) * 256 + n];
            const unsigned short hi = f2bf(f);
            const unsigned short lo = f2bf(f - bf2f(hi));
            wB[hbase + i] = hi;
            wB[lbase + i] = lo;
        }
    }
}

// A-fragment convention per wave (8 samples), built fully in registers:
//   aF0 rows 0-7: h_hi(sample=row), rows 8-15: h_lo(sample=row-8)
//   aF1 rows 0-7: ta_hi,            rows 8-15: tb_hi
//   aF2 rows 0-7: ta_lo,            rows 8-15: tb_lo
// Lane l holds A[row=l&15][k = ks*32 + (l>>4)*8 + i]; lanes l and l+8 redundantly
// compute the same sample's activations (one keeps hi, one keeps lo).
__global__ __launch_bounds__(NTHREADS, 2)
void lode_mfma(const float* __restrict__ x,
               const float4* __restrict__ w0p, const float* __restrict__ b0,
               const unsigned short* __restrict__ wB,
               const float* __restrict__ b1,
               const float4* __restrict__ hwp,
               const float* __restrict__ bd, const float* __restrict__ bo,
               float* __restrict__ out, int n)
{
    __shared__ uint4 S[2048];   // 32 KB B double-buffer (16 KB per nt-tile)

    const int tid  = threadIdx.x;
    const int wave = tid >> 6;
    const int lane = tid & 63;
    const int r15  = lane & 15;
    const int sLoc = r15 & 7;
    const bool isLo = (r15 >= 8);
    const int kg   = lane >> 4;

    // ---------------- phase 1: in-register A fragments (libm math) ----------------
    int sg1 = blockIdx.x * SB + wave * 8 + sLoc;
    if (sg1 >= n) sg1 = n - 1;
    const float q0 = x[sg1 * 6 + 0];
    const float q1 = x[sg1 * 6 + 1];
    float sn0, cs0, sn1, cs1;
    sincosf(q0, &sn0, &cs0);
    sincosf(q1, &sn1, &cs1);
    const float sA = isLo ? sn1 : sn0;
    const float cA = isLo ? cs1 : cs0;

    short8 aF0[8], aF1[8], aF2[8];
    #pragma unroll
    for (int ks = 0; ks < 8; ++ks) {
        unsigned wH[4], wT[4], wL[4];
        #pragma unroll
        for (int p = 0; p < 4; ++p) {
            const int j0 = ks * 32 + kg * 8 + 2 * p;
            const float4 wa = w0p[j0];
            const float4 wb = w0p[j0 + 1];
            const float2 bb = *reinterpret_cast<const float2*>(&b0[j0]);
            float z0 = bb.x;
            z0 = fmaf(cs0, wa.x, z0); z0 = fmaf(cs1, wa.y, z0);
            z0 = fmaf(sn0, wa.z, z0); z0 = fmaf(sn1, wa.w, z0);
            float z1 = bb.y;
            z1 = fmaf(cs0, wb.x, z1); z1 = fmaf(cs1, wb.y, z1);
            z1 = fmaf(sn0, wb.z, z1); z1 = fmaf(sn1, wb.w, z1);
            const float h0 = tanhf(z0);
            const float h1 = tanhf(z1);
            const unsigned short h0h = f2bf(h0);
            const unsigned short h1h = f2bf(h1);
            const unsigned short h0l = f2bf(h0 - bf2f(h0h));
            const unsigned short h1l = f2bf(h1 - bf2f(h1h));
            const float dt0 = fmaf(-h0, h0, 1.f);
            const float dt1 = fmaf(-h1, h1, 1.f);
            const float wx0 = isLo ? wa.y : wa.x, wz0 = isLo ? wa.w : wa.z;
            const float wx1 = isLo ? wb.y : wb.x, wz1 = isLo ? wb.w : wb.z;
            const float t0 = dt0 * fmaf(-sA, wx0, cA * wz0);
            const float t1 = dt1 * fmaf(-sA, wx1, cA * wz1);
            const unsigned short t0h = f2bf(t0);
            const unsigned short t1h = f2bf(t1);
            const unsigned short t0l = f2bf(t0 - bf2f(t0h));
            const unsigned short t1l = f2bf(t1 - bf2f(t1h));
            wH[p] = isLo ? pack2(h0l, h1l) : pack2(h0h, h1h);
            wT[p] = pack2(t0h, t1h);
            wL[p] = pack2(t0l, t1l);
        }
        aF0[ks] = __builtin_bit_cast(short8, make_uint4(wH[0], wH[1], wH[2], wH[3]));
        aF1[ks] = __builtin_bit_cast(short8, make_uint4(wT[0], wT[1], wT[2], wT[3]));
        aF2[ks] = __builtin_bit_cast(short8, make_uint4(wL[0], wL[1], wL[2], wL[3]));
    }

    // ---------------- stage nt=0 into buffer 0 (r2-proven path) ----------------
    {
        const char* src = (const char*)wB;
        #pragma unroll
        for (int g = 0; g < 4; ++g) {
            const int chunk = g * 4 + wave;
            __builtin_amdgcn_global_load_lds(
                (const __attribute__((address_space(1))) void*)(src + chunk * 1024 + lane * 16),
                (__attribute__((address_space(3))) void*)&S[chunk * 64 + lane], 16, 0, 0);
        }
    }
    __syncthreads();

    float ph0[4] = {0,0,0,0}, ph1[4] = {0,0,0,0}, pho[4] = {0,0,0,0};
    float pt0[4] = {0,0,0,0}, pt1[4] = {0,0,0,0}, pto[4] = {0,0,0,0}, ptv[4] = {0,0,0,0};
    const int col = lane & 15;

    #pragma unroll 1
    for (int nt = 0; nt < 16; ++nt) {
        // prefetch nt+1 into the other buffer (wraps harmlessly at nt=15)
        {
            const int ntn = (nt + 1) & 15;
            const int bn  = (nt + 1) & 1;
            const char* src = (const char*)wB + ntn * 16384;
            #pragma unroll
            for (int g = 0; g < 4; ++g) {
                const int chunk = g * 4 + wave;
                __builtin_amdgcn_global_load_lds(
                    (const __attribute__((address_space(1))) void*)(src + chunk * 1024 + lane * 16),
                    (__attribute__((address_space(3))) void*)&S[bn * 1024 + chunk * 64 + lane],
                    16, 0, 0);
            }
        }

        const int ncol = nt * 16 + col;
        const float4 hw  = hwp[ncol];
        const float  b1v = b1[ncol];

        const uint4* Bb = &S[(nt & 1) * 1024];
        f32x4 c1a = {0.f,0.f,0.f,0.f};   // {h_hi,h_lo} x W_hi
        f32x4 c2  = {0.f,0.f,0.f,0.f};   // {h_hi,h_lo} x W_lo
        f32x4 c3  = {0.f,0.f,0.f,0.f};   // {ta_hi,tb_hi} x W_hi
        f32x4 c4  = {0.f,0.f,0.f,0.f};   // {ta_hi,tb_hi} x W_lo
        f32x4 c5  = {0.f,0.f,0.f,0.f};   // {ta_lo,tb_lo} x W_hi
        #pragma unroll
        for (int ks = 0; ks < 8; ++ks) {
            const short8 bh = *reinterpret_cast<const short8*>(&Bb[ks * 64 + lane]);
            const short8 bl = *reinterpret_cast<const short8*>(&Bb[512 + ks * 64 + lane]);
            c1a = __builtin_amdgcn_mfma_f32_16x16x32_bf16(aF0[ks], bh, c1a, 0, 0, 0);
            c2  = __builtin_amdgcn_mfma_f32_16x16x32_bf16(aF0[ks], bl, c2,  0, 0, 0);
            c3  = __builtin_amdgcn_mfma_f32_16x16x32_bf16(aF1[ks], bh, c3,  0, 0, 0);
            c4  = __builtin_amdgcn_mfma_f32_16x16x32_bf16(aF1[ks], bl, c4,  0, 0, 0);
            c5  = __builtin_amdgcn_mfma_f32_16x16x32_bf16(aF2[ks], bh, c5,  0, 0, 0);
        }

        // epilogue: lanes<32 = rows 0-7 (h_hi part / ta); lanes>=32 = rows 8-15 (h_lo / tb)
        #pragma unroll
        for (int r = 0; r < 4; ++r) {
            const float zs = c1a[r] + c2[r];
            const float zp = __shfl_xor(zs, 32);
            const float z  = zs + zp + b1v;
            const float h1 = tanhf(z);
            const float dt = fmaf(-h1, h1, 1.f);
            const float tt = c3[r] + c4[r] + c5[r];
            const float t1 = dt * tt;                 // ta lanes<32, tb lanes>=32
            ph0[r] = fmaf(h1, hw.x, ph0[r]);
            ph1[r] = fmaf(h1, hw.y, ph1[r]);
            pho[r] = fmaf(h1, hw.z, pho[r]);
            pt0[r] = fmaf(t1, hw.x, pt0[r]);
            pt1[r] = fmaf(t1, hw.y, pt1[r]);
            pto[r] = fmaf(t1, hw.z, pto[r]);
            ptv[r] = fmaf(t1, hw.w, ptv[r]);
        }
        __syncthreads();
    }

    // ---------------- column reduction across 16 lanes ----------------
    #pragma unroll
    for (int r = 0; r < 4; ++r) {
        #pragma unroll
        for (int m = 1; m < 16; m <<= 1) {
            ph0[r] += __shfl_xor(ph0[r], m);
            ph1[r] += __shfl_xor(ph1[r], m);
            pho[r] += __shfl_xor(pho[r], m);
            pt0[r] += __shfl_xor(pt0[r], m);
            pt1[r] += __shfl_xor(pt1[r], m);
            pto[r] += __shfl_xor(pto[r], m);
            ptv[r] += __shfl_xor(ptv[r], m);
        }
    }
    float qt0[4], qt1[4], qto[4], qtv[4];
    #pragma unroll
    for (int r = 0; r < 4; ++r) {
        qt0[r] = __shfl_xor(pt0[r], 32);
        qt1[r] = __shfl_xor(pt1[r], 32);
        qto[r] = __shfl_xor(pto[r], 32);
        qtv[r] = __shfl_xor(ptv[r], 32);
    }

    if (lane < 32 && (lane & 15) == 0) {
        const float bd0 = bd[0], bd1 = bd[1], bo0 = bo[0];
        #pragma unroll
        for (int r = 0; r < 4; ++r) {
            const int s  = ((lane >> 4) << 2) + r;
            const int sg = blockIdx.x * SB + wave * 8 + s;
            if (sg < n) {
                const float u    = x[sg * 6 + 2];
                const float vv   = x[sg * 6 + 3];
                const float tau0 = x[sg * 6 + 4];
                const float tau1 = x[sg * 6 + 5];

                const float zd0 = ph0[r] + bd0;
                const float zd1 = ph1[r] + bd1;
                const float zo  = pho[r] + bo0;

                const float ld0 = softplus_f(zd0) + 1e-4f;
                const float ld1 = softplus_f(zd1) + 1e-4f;
                const float lo  = zo;

                const float sg0 = 1.f / (1.f + expf(-zd0));
                const float sg1 = 1.f / (1.f + expf(-zd1));

                const float pa_d0 = pt0[r], pa_d1 = pt1[r], pa_o = pto[r], pa_v = ptv[r];
                const float pb_d0 = qt0[r], pb_d1 = qt1[r], pb_o = qto[r], pb_v = qtv[r];

                const float ld0a = sg0 * pa_d0, ld0b = sg0 * pb_d0;
                const float ld1a = sg1 * pa_d1, ld1b = sg1 * pb_d1;
                const float loa  = pa_o,        lob  = pb_o;
                const float ga   = pa_v,        gb   = pb_v;

                const float H00 = fmaf(ld0, ld0, 1e-4f);
                const float H01 = ld0 * lo;
                const float H11 = fmaf(lo, lo, fmaf(ld1, ld1, 1e-4f));

                const float dH00a = 2.f * ld0 * ld0a, dH00b = 2.f * ld0 * ld0b;
                const float dH01a = fmaf(ld0a, lo, ld0 * loa);
                const float dH01b = fmaf(ld0b, lo, ld0 * lob);
                const float dH11a = 2.f * fmaf(lo, loa, ld1 * ld1a);
                const float dH11b = 2.f * fmaf(lo, lob, ld1 * ld1b);

                const float wa0 = fmaf(dH00a, u, dH01a * vv);
                const float wa1 = fmaf(dH01a, u, dH11a * vv);
                const float wb0 = fmaf(dH00b, u, dH01b * vv);
                const float wb1 = fmaf(dH01b, u, dH11b * vv);

                const float QFa = dH00a*u*u + 2.f*dH01a*u*vv + dH11a*vv*vv;
                const float QFb = dH00b*u*u + 2.f*dH01b*u*vv + dH11b*vv*vv;

                const float C0 = fmaf(wa0, u, wb0 * vv) - 0.5f * QFa;
                const float C1 = fmaf(wa1, u, wb1 * vv) - 0.5f * QFb;

                const float r0 = tau0 - C0 - ga;
                const float r1 = tau1 - C1 - gb;

                const float det = fmaf(H00, H11, -H01 * H01);
                const float inv = 1.f / det;
                const float qdd0 = (H11 * r0 - H01 * r1) * inv;
                const float qdd1 = (H00 * r1 - H01 * r0) * inv;

                float2* o = reinterpret_cast<float2*>(&out[sg * 6]);
                o[0] = make_float2(u, vv);
                o[1] = make_float2(qdd0, qdd1);
                o[2] = make_float2(0.f, 0.f);
            }
        }
    }
}

extern "C" void kernel_launch(void* const* d_in, const int* in_sizes, int n_in,
                              void* d_out, int out_size, void* d_ws, size_t ws_size,
                              hipStream_t stream) {
    // dict order: t, x, W0, b0, W1, b1, Wd, bd, Wo, bo, Wv, bv
    const float* x  = (const float*)d_in[1];
    const float* W0 = (const float*)d_in[2];
    const float* b0 = (const float*)d_in[3];
    const float* W1 = (const float*)d_in[4];
    const float* b1 = (const float*)d_in[5];
    const float* Wd = (const float*)d_in[6];
    const float* bd = (const float*)d_in[7];
    const float* Wo = (const float*)d_in[8];
    const float* bo = (const float*)d_in[9];
    const float* Wv = (const float*)d_in[10];
    float* out = (float*)d_out;

    unsigned short* wB = (unsigned short*)d_ws;                         // 256 KB
    float4* w0p = (float4*)((char*)d_ws + 262144);                      // 4 KB
    float4* hwp = (float4*)((char*)d_ws + 262144 + 4096);               // 4 KB

    const int n = in_sizes[1] / 6;

    prep<<<32, 256, 0, stream>>>(W1, W0, Wd, Wo, Wv, wB, w0p, hwp);

    const int grid = (n + SB - 1) / SB;
    lode_mfma<<<grid, NTHREADS, 0, stream>>>(x, w0p, b0, wB, b1, hwp, bd, bo, out, n);
}

// Round 7
// 526.695 us; speedup vs baseline: 1.2413x; 1.0575x over previous
//
#include <hip/hip_runtime.h>
#include <math.h>

#define SB 32          // samples per block (8 per wave)
#define NTHREADS 256   // 4 waves

typedef short short8 __attribute__((ext_vector_type(8)));
typedef float f32x4  __attribute__((ext_vector_type(4)));

__device__ __forceinline__ unsigned short f2bf(float f) {
    unsigned int u = __builtin_bit_cast(unsigned int, f);
    unsigned int r = (u + 0x7FFFu + ((u >> 16) & 1u)) >> 16;   // RNE
    return (unsigned short)r;
}
__device__ __forceinline__ float bf2f(unsigned short h) {
    unsigned int u = ((unsigned int)h) << 16;
    return __builtin_bit_cast(float, u);
}
__device__ __forceinline__ unsigned pack2(unsigned short lo, unsigned short hi) {
    return (unsigned)lo | ((unsigned)hi << 16);
}
__device__ __forceinline__ float softplus_f(float z) {
    return z > 15.f ? z : log1pf(expf(z));
}

// ---------------- prep: pack W1 (split hi/lo) + W0 + head weights ----------------
// wB layout (short8 slots): nt*1024 + [hi: ks*64+l | lo: 512+ks*64+l]
// slot element i: B[k][n], k = ks*32 + (l>>4)*8 + i, n = nt*16 + (l&15)
__global__ void prep(const float* __restrict__ W1, const float* __restrict__ W0,
                     const float* __restrict__ Wd, const float* __restrict__ Wo,
                     const float* __restrict__ Wv,
                     unsigned short* __restrict__ wB,
                     float4* __restrict__ w0p, float4* __restrict__ hwp)
{
    int idx = blockIdx.x * blockDim.x + threadIdx.x;
    if (idx < 256) {
        w0p[idx] = make_float4(W0[idx], W0[256 + idx], W0[512 + idx], W0[768 + idx]);
        hwp[idx] = make_float4(Wd[2 * idx], Wd[2 * idx + 1], Wo[idx], Wv[idx]);
    }
    if (idx < 8192) {
        const int l  = idx & 63;
        const int ks = (idx >> 6) & 7;
        const int nt = idx >> 9;
        const int k0 = ks * 32 + (l >> 4) * 8;
        const int n  = nt * 16 + (l & 15);
        const int hbase = (nt * 1024 + ks * 64 + l) * 8;
        const int lbase = (nt * 1024 + 512 + ks * 64 + l) * 8;
        #pragma unroll
        for (int i = 0; i < 8; ++i) {
            const float f = W1[(k0 + i) * 256 + n];
            const unsigned short hi = f2bf(f);
            const unsigned short lo = f2bf(f - bf2f(hi));
            wB[hbase + i] = hi;
            wB[lbase + i] = lo;
        }
    }
}

// A-fragment convention per wave (8 samples), built fully in registers:
//   aF0 rows 0-7: h_hi(sample=row), rows 8-15: h_lo(sample=row-8)
//   aF1 rows 0-7: ta_hi,            rows 8-15: tb_hi
// Lane l holds A[row=l&15][k = ks*32 + (l>>4)*8 + i]; lanes l and l+8 redundantly
// compute the same sample's activations (one keeps hi, one keeps lo).
__global__ __launch_bounds__(NTHREADS, 1)
void lode_mfma(const float* __restrict__ x,
               const float4* __restrict__ w0p, const float* __restrict__ b0,
               const unsigned short* __restrict__ wB,
               const float* __restrict__ b1,
               const float4* __restrict__ hwp,
               const float* __restrict__ bd, const float* __restrict__ bo,
               float* __restrict__ out, int n)
{
    __shared__ uint4 S[2048];   // 32 KB B double-buffer (16 KB per nt-tile)

    const int tid  = threadIdx.x;
    const int wave = tid >> 6;
    const int lane = tid & 63;
    const int r15  = lane & 15;
    const int sLoc = r15 & 7;
    const bool isLo = (r15 >= 8);
    const int kg   = lane >> 4;

    // ---------------- phase 1: in-register A fragments (libm math) ----------------
    int sg1 = blockIdx.x * SB + wave * 8 + sLoc;
    if (sg1 >= n) sg1 = n - 1;
    const float q0 = x[sg1 * 6 + 0];
    const float q1 = x[sg1 * 6 + 1];
    float sn0, cs0, sn1, cs1;
    sincosf(q0, &sn0, &cs0);
    sincosf(q1, &sn1, &cs1);
    const float sA = isLo ? sn1 : sn0;
    const float cA = isLo ? cs1 : cs0;

    short8 aF0[8], aF1[8];
    #pragma unroll
    for (int ks = 0; ks < 8; ++ks) {
        unsigned wH[4], wT[4];
        #pragma unroll
        for (int p = 0; p < 4; ++p) {
            const int j0 = ks * 32 + kg * 8 + 2 * p;
            const float4 wa = w0p[j0];
            const float4 wb = w0p[j0 + 1];
            const float2 bb = *reinterpret_cast<const float2*>(&b0[j0]);
            float z0 = bb.x;
            z0 = fmaf(cs0, wa.x, z0); z0 = fmaf(cs1, wa.y, z0);
            z0 = fmaf(sn0, wa.z, z0); z0 = fmaf(sn1, wa.w, z0);
            float z1 = bb.y;
            z1 = fmaf(cs0, wb.x, z1); z1 = fmaf(cs1, wb.y, z1);
            z1 = fmaf(sn0, wb.z, z1); z1 = fmaf(sn1, wb.w, z1);
            const float h0 = tanhf(z0);
            const float h1 = tanhf(z1);
            const unsigned short h0h = f2bf(h0);
            const unsigned short h1h = f2bf(h1);
            const unsigned short h0l = f2bf(h0 - bf2f(h0h));
            const unsigned short h1l = f2bf(h1 - bf2f(h1h));
            const float dt0 = fmaf(-h0, h0, 1.f);
            const float dt1 = fmaf(-h1, h1, 1.f);
            const float wx0 = isLo ? wa.y : wa.x, wz0 = isLo ? wa.w : wa.z;
            const float wx1 = isLo ? wb.y : wb.x, wz1 = isLo ? wb.w : wb.z;
            const float t0 = dt0 * fmaf(-sA, wx0, cA * wz0);
            const float t1 = dt1 * fmaf(-sA, wx1, cA * wz1);
            const unsigned short t0h = f2bf(t0);
            const unsigned short t1h = f2bf(t1);
            wH[p] = isLo ? pack2(h0l, h1l) : pack2(h0h, h1h);
            wT[p] = pack2(t0h, t1h);
        }
        aF0[ks] = __builtin_bit_cast(short8, make_uint4(wH[0], wH[1], wH[2], wH[3]));
        aF1[ks] = __builtin_bit_cast(short8, make_uint4(wT[0], wT[1], wT[2], wT[3]));
    }

    // ---------------- stage nt=0 into buffer 0 ----------------
    {
        const char* src = (const char*)wB;
        #pragma unroll
        for (int g = 0; g < 4; ++g) {
            const int chunk = g * 4 + wave;
            __builtin_amdgcn_global_load_lds(
                (const __attribute__((address_space(1))) void*)(src + chunk * 1024 + lane * 16),
                (__attribute__((address_space(3))) void*)&S[chunk * 64 + lane], 16, 0, 0);
        }
    }
    __syncthreads();

    float ph0[4] = {0,0,0,0}, ph1[4] = {0,0,0,0}, pho[4] = {0,0,0,0};
    float pt0[4] = {0,0,0,0}, pt1[4] = {0,0,0,0}, pto[4] = {0,0,0,0}, ptv[4] = {0,0,0,0};
    const int col = lane & 15;

    #pragma unroll 1
    for (int nt = 0; nt < 16; ++nt) {
        // prefetch nt+1 into the other buffer (wraps harmlessly at nt=15)
        {
            const int ntn = (nt + 1) & 15;
            const int bn  = (nt + 1) & 1;
            const char* src = (const char*)wB + ntn * 16384;
            #pragma unroll
            for (int g = 0; g < 4; ++g) {
                const int chunk = g * 4 + wave;
                __builtin_amdgcn_global_load_lds(
                    (const __attribute__((address_space(1))) void*)(src + chunk * 1024 + lane * 16),
                    (__attribute__((address_space(3))) void*)&S[bn * 1024 + chunk * 64 + lane],
                    16, 0, 0);
            }
        }

        const int ncol = nt * 16 + col;
        const float4 hw  = hwp[ncol];
        const float  b1v = b1[ncol];

        const uint4* Bb = &S[(nt & 1) * 1024];
        f32x4 c1a = {0.f,0.f,0.f,0.f};   // {h_hi,h_lo} x W_hi
        f32x4 c2  = {0.f,0.f,0.f,0.f};   // {h_hi,h_lo} x W_lo
        f32x4 c3  = {0.f,0.f,0.f,0.f};   // {ta_hi,tb_hi} x W_hi
        f32x4 c4  = {0.f,0.f,0.f,0.f};   // {ta_hi,tb_hi} x W_lo
        #pragma unroll
        for (int ks = 0; ks < 8; ++ks) {
            const short8 bh = *reinterpret_cast<const short8*>(&Bb[ks * 64 + lane]);
            const short8 bl = *reinterpret_cast<const short8*>(&Bb[512 + ks * 64 + lane]);
            c1a = __builtin_amdgcn_mfma_f32_16x16x32_bf16(aF0[ks], bh, c1a, 0, 0, 0);
            c2  = __builtin_amdgcn_mfma_f32_16x16x32_bf16(aF0[ks], bl, c2,  0, 0, 0);
            c3  = __builtin_amdgcn_mfma_f32_16x16x32_bf16(aF1[ks], bh, c3,  0, 0, 0);
            c4  = __builtin_amdgcn_mfma_f32_16x16x32_bf16(aF1[ks], bl, c4,  0, 0, 0);
        }

        // epilogue: lanes<32 = rows 0-7 (h_hi part / ta); lanes>=32 = rows 8-15 (h_lo / tb)
        #pragma unroll
        for (int r = 0; r < 4; ++r) {
            const float zs = c1a[r] + c2[r];
            const float zp = __shfl_xor(zs, 32);
            const float z  = zs + zp + b1v;
            const float h1 = tanhf(z);
            const float dt = fmaf(-h1, h1, 1.f);
            const float tt = c3[r] + c4[r];
            const float t1 = dt * tt;                 // ta lanes<32, tb lanes>=32
            ph0[r] = fmaf(h1, hw.x, ph0[r]);
            ph1[r] = fmaf(h1, hw.y, ph1[r]);
            pho[r] = fmaf(h1, hw.z, pho[r]);
            pt0[r] = fmaf(t1, hw.x, pt0[r]);
            pt1[r] = fmaf(t1, hw.y, pt1[r]);
            pto[r] = fmaf(t1, hw.z, pto[r]);
            ptv[r] = fmaf(t1, hw.w, ptv[r]);
        }
        __syncthreads();
    }

    // ---------------- column reduction across 16 lanes ----------------
    #pragma unroll
    for (int r = 0; r < 4; ++r) {
        #pragma unroll
        for (int m = 1; m < 16; m <<= 1) {
            ph0[r] += __shfl_xor(ph0[r], m);
            ph1[r] += __shfl_xor(ph1[r], m);
            pho[r] += __shfl_xor(pho[r], m);
            pt0[r] += __shfl_xor(pt0[r], m);
            pt1[r] += __shfl_xor(pt1[r], m);
            pto[r] += __shfl_xor(pto[r], m);
            ptv[r] += __shfl_xor(ptv[r], m);
        }
    }
    float qt0[4], qt1[4], qto[4], qtv[4];
    #pragma unroll
    for (int r = 0; r < 4; ++r) {
        qt0[r] = __shfl_xor(pt0[r], 32);
        qt1[r] = __shfl_xor(pt1[r], 32);
        qto[r] = __shfl_xor(pto[r], 32);
        qtv[r] = __shfl_xor(ptv[r], 32);
    }

    if (lane < 32 && (lane & 15) == 0) {
        const float bd0 = bd[0], bd1 = bd[1], bo0 = bo[0];
        #pragma unroll
        for (int r = 0; r < 4; ++r) {
            const int s  = ((lane >> 4) << 2) + r;
            const int sg = blockIdx.x * SB + wave * 8 + s;
            if (sg < n) {
                const float u    = x[sg * 6 + 2];
                const float vv   = x[sg * 6 + 3];
                const float tau0 = x[sg * 6 + 4];
                const float tau1 = x[sg * 6 + 5];

                const float zd0 = ph0[r] + bd0;
                const float zd1 = ph1[r] + bd1;
                const float zo  = pho[r] + bo0;

                const float ld0 = softplus_f(zd0) + 1e-4f;
                const float ld1 = softplus_f(zd1) + 1e-4f;
                const float lo  = zo;

                const float sg0 = 1.f / (1.f + expf(-zd0));
                const float sg1 = 1.f / (1.f + expf(-zd1));

                const float pa_d0 = pt0[r], pa_d1 = pt1[r], pa_o = pto[r], pa_v = ptv[r];
                const float pb_d0 = qt0[r], pb_d1 = qt1[r], pb_o = qto[r], pb_v = qtv[r];

                const float ld0a = sg0 * pa_d0, ld0b = sg0 * pb_d0;
                const float ld1a = sg1 * pa_d1, ld1b = sg1 * pb_d1;
                const float loa  = pa_o,        lob  = pb_o;
                const float ga   = pa_v,        gb   = pb_v;

                const float H00 = fmaf(ld0, ld0, 1e-4f);
                const float H01 = ld0 * lo;
                const float H11 = fmaf(lo, lo, fmaf(ld1, ld1, 1e-4f));

                const float dH00a = 2.f * ld0 * ld0a, dH00b = 2.f * ld0 * ld0b;
                const float dH01a = fmaf(ld0a, lo, ld0 * loa);
                const float dH01b = fmaf(ld0b, lo, ld0 * lob);
                const float dH11a = 2.f * fmaf(lo, loa, ld1 * ld1a);
                const float dH11b = 2.f * fmaf(lo, lob, ld1 * ld1b);

                const float wa0 = fmaf(dH00a, u, dH01a * vv);
                const float wa1 = fmaf(dH01a, u, dH11a * vv);
                const float wb0 = fmaf(dH00b, u, dH01b * vv);
                const float wb1 = fmaf(dH01b, u, dH11b * vv);

                const float QFa = dH00a*u*u + 2.f*dH01a*u*vv + dH11a*vv*vv;
                const float QFb = dH00b*u*u + 2.f*dH01b*u*vv + dH11b*vv*vv;

                const float C0 = fmaf(wa0, u, wb0 * vv) - 0.5f * QFa;
                const float C1 = fmaf(wa1, u, wb1 * vv) - 0.5f * QFb;

                const float r0 = tau0 - C0 - ga;
                const float r1 = tau1 - C1 - gb;

                const float det = fmaf(H00, H11, -H01 * H01);
                const float inv = 1.f / det;
                const float qdd0 = (H11 * r0 - H01 * r1) * inv;
                const float qdd1 = (H00 * r1 - H01 * r0) * inv;

                float2* o = reinterpret_cast<float2*>(&out[sg * 6]);
                o[0] = make_float2(u, vv);
                o[1] = make_float2(qdd0, qdd1);
                o[2] = make_float2(0.f, 0.f);
            }
        }
    }
}

extern "C" void kernel_launch(void* const* d_in, const int* in_sizes, int n_in,
                              void* d_out, int out_size, void* d_ws, size_t ws_size,
                              hipStream_t stream) {
    // dict order: t, x, W0, b0, W1, b1, Wd, bd, Wo, bo, Wv, bv
    const float* x  = (const float*)d_in[1];
    const float* W0 = (const float*)d_in[2];
    const float* b0 = (const float*)d_in[3];
    const float* W1 = (const float*)d_in[4];
    const float* b1 = (const float*)d_in[5];
    const float* Wd = (const float*)d_in[6];
    const float* bd = (const float*)d_in[7];
    const float* Wo = (const float*)d_in[8];
    const float* bo = (const float*)d_in[9];
    const float* Wv = (const float*)d_in[10];
    float* out = (float*)d_out;

    unsigned short* wB = (unsigned short*)d_ws;                         // 256 KB
    float4* w0p = (float4*)((char*)d_ws + 262144);                      // 4 KB
    float4* hwp = (float4*)((char*)d_ws + 262144 + 4096);               // 4 KB

    const int n = in_sizes[1] / 6;

    prep<<<32, 256, 0, stream>>>(W1, W0, Wd, Wo, Wv, wB, w0p, hwp);

    const int grid = (n + SB - 1) / SB;
    lode_mfma<<<grid, NTHREADS, 0, stream>>>(x, w0p, b0, wB, b1, hwp, bd, bo, out, n);
}

// Round 8
// 296.251 us; speedup vs baseline: 2.2069x; 1.7779x over previous
//
#include <hip/hip_runtime.h>
#include <math.h>

#define SB 32          // samples per block (4 per wave, 8 waves)
#define NTHREADS 512

typedef short short8 __attribute__((ext_vector_type(8)));
typedef float f32x4  __attribute__((ext_vector_type(4)));

__device__ __forceinline__ unsigned short f2bf(float f) {
    unsigned int u = __builtin_bit_cast(unsigned int, f);
    unsigned int r = (u + 0x7FFFu + ((u >> 16) & 1u)) >> 16;   // RNE
    return (unsigned short)r;
}
__device__ __forceinline__ float bf2f(unsigned short h) {
    unsigned int u = ((unsigned int)h) << 16;
    return __builtin_bit_cast(float, u);
}
__device__ __forceinline__ unsigned pack2(unsigned short lo, unsigned short hi) {
    return (unsigned)lo | ((unsigned)hi << 16);
}
__device__ __forceinline__ float softplus_f(float z) {
    return z > 15.f ? z : log1pf(expf(z));
}
__device__ __forceinline__ unsigned selv(bool c, unsigned a, unsigned b) {
    return c ? a : b;
}
__device__ __forceinline__ unsigned sx(unsigned v, int m) {
    return (unsigned)__shfl_xor((int)v, m);
}

// ---------------- prep: pack W1 (split hi/lo) + W0 + head weights ----------------
__global__ void prep(const float* __restrict__ W1, const float* __restrict__ W0,
                     const float* __restrict__ Wd, const float* __restrict__ Wo,
                     const float* __restrict__ Wv,
                     unsigned short* __restrict__ wB,
                     float4* __restrict__ w0p, float4* __restrict__ hwp)
{
    int idx = blockIdx.x * blockDim.x + threadIdx.x;
    if (idx < 256) {
        w0p[idx] = make_float4(W0[idx], W0[256 + idx], W0[512 + idx], W0[768 + idx]);
        hwp[idx] = make_float4(Wd[2 * idx], Wd[2 * idx + 1], Wo[idx], Wv[idx]);
    }
    if (idx < 8192) {
        const int l  = idx & 63;
        const int ks = (idx >> 6) & 7;
        const int nt = idx >> 9;
        const int k0 = ks * 32 + (l >> 4) * 8;
        const int n  = nt * 16 + (l & 15);
        const int hbase = (nt * 1024 + ks * 64 + l) * 8;
        const int lbase = (nt * 1024 + 512 + ks * 64 + l) * 8;
        #pragma unroll
        for (int i = 0; i < 8; ++i) {
            const float f = W1[(k0 + i) * 256 + n];
            const unsigned short hi = f2bf(f);
            const unsigned short lo = f2bf(f - bf2f(hi));
            wB[hbase + i] = hi;
            wB[lbase + i] = lo;
        }
    }
}

// A rows (16): row = rho*4 + s ; rho: 0=h_hi, 1=h_lo, 2=ta, 3=tb ; s = sample 0..3.
// Lane l: r15=l&15 -> (rho=r15>>2, s=r15&3), kg=l>>4; element i -> k=ks*32+kg*8+i.
// Phase-1 dedupe: lane computes neurons j = ks*32+kg*8+2*rho+{0,1} for sample s
// (2 tanh instead of 8) and produces ALL four pack types; a 4-lane shuffle
// transpose (xor 4/8/12) then gives each lane its own row-type for all 4 pairs.
__global__ __launch_bounds__(NTHREADS, 4)
void lode_mfma(const float* __restrict__ x,
               const float4* __restrict__ w0p, const float* __restrict__ b0,
               const unsigned short* __restrict__ wB,
               const float* __restrict__ b1,
               const float4* __restrict__ hwp,
               const float* __restrict__ bd, const float* __restrict__ bo,
               float* __restrict__ out, int n)
{
    __shared__ uint4 S[2048];   // 32 KB B double-buffer

    const int tid  = threadIdx.x;
    const int wave = tid >> 6;
    const int lane = tid & 63;
    const int r15  = lane & 15;
    const int s    = r15 & 3;
    const int rho  = r15 >> 2;
    const bool rb0 = (rho & 1) != 0;
    const bool rb1 = (rho & 2) != 0;

    // ---------------- phase 1: in-register A fragments ----------------
    int sg1 = blockIdx.x * SB + wave * 4 + s;
    if (sg1 >= n) sg1 = n - 1;
    const float qq0 = x[sg1 * 6 + 0];
    const float qq1 = x[sg1 * 6 + 1];
    // sincos dedupe: even rho computes q0's pair, odd rho computes q1's; exchange xor4
    float ss_, cc_;
    sincosf(rb0 ? qq1 : qq0, &ss_, &cc_);
    const float ss_o = __shfl_xor(ss_, 4);
    const float cc_o = __shfl_xor(cc_, 4);
    const float sn0 = rb0 ? ss_o : ss_;
    const float cs0 = rb0 ? cc_o : cc_;
    const float sn1 = rb0 ? ss_ : ss_o;
    const float cs1 = rb0 ? cc_ : cc_o;

    short8 aF[8];
    #pragma unroll
    for (int ks = 0; ks < 8; ++ks) {
        const int kg = lane >> 4;
        const int j0 = ks * 32 + kg * 8 + 2 * rho;
        const float4 wa = w0p[j0];
        const float4 wb = w0p[j0 + 1];
        const float2 bb = *reinterpret_cast<const float2*>(&b0[j0]);
        float z0 = bb.x;
        z0 = fmaf(cs0, wa.x, z0); z0 = fmaf(cs1, wa.y, z0);
        z0 = fmaf(sn0, wa.z, z0); z0 = fmaf(sn1, wa.w, z0);
        float z1 = bb.y;
        z1 = fmaf(cs0, wb.x, z1); z1 = fmaf(cs1, wb.y, z1);
        z1 = fmaf(sn0, wb.z, z1); z1 = fmaf(sn1, wb.w, z1);
        const float h0 = tanhf(z0);
        const float h1 = tanhf(z1);
        const unsigned short h0h = f2bf(h0);
        const unsigned short h1h = f2bf(h1);
        const unsigned short h0l = f2bf(h0 - bf2f(h0h));
        const unsigned short h1l = f2bf(h1 - bf2f(h1h));
        const float dt0 = fmaf(-h0, h0, 1.f);
        const float dt1 = fmaf(-h1, h1, 1.f);
        const float ta0 = dt0 * fmaf(-sn0, wa.x, cs0 * wa.z);
        const float ta1 = dt1 * fmaf(-sn0, wb.x, cs0 * wb.z);
        const float tb0 = dt0 * fmaf(-sn1, wa.y, cs1 * wa.w);
        const float tb1 = dt1 * fmaf(-sn1, wb.y, cs1 * wb.w);
        const unsigned v0 = pack2(h0h, h1h);                       // type 0: h_hi
        const unsigned v1 = pack2(h0l, h1l);                       // type 1: h_lo
        const unsigned v2 = pack2(f2bf(ta0), f2bf(ta1));           // type 2: ta
        const unsigned v3 = pack2(f2bf(tb0), f2bf(tb1));           // type 3: tb
        // gather v[rho^k] via selects, exchange via xor 4/8/12
        const unsigned s0 = selv(rb1, selv(rb0, v3, v2), selv(rb0, v1, v0)); // v[rho]
        const unsigned s1 = selv(rb1, selv(rb0, v2, v3), selv(rb0, v0, v1)); // v[rho^1]
        const unsigned s2 = selv(rb1, selv(rb0, v1, v0), selv(rb0, v3, v2)); // v[rho^2]
        const unsigned s3 = selv(rb1, selv(rb0, v0, v1), selv(rb0, v2, v3)); // v[rho^3]
        const unsigned r4  = sx(s1, 4);
        const unsigned r8  = sx(s2, 8);
        const unsigned r12 = sx(s3, 12);
        // w[p]: own-type pack for pair p
        const unsigned w0 = selv(rb1, selv(rb0, r12, r8), selv(rb0, r4, s0));
        const unsigned w1 = selv(rb1, selv(rb0, r8, r12), selv(rb0, s0, r4));
        const unsigned w2 = selv(rb1, selv(rb0, r4, s0), selv(rb0, r12, r8));
        const unsigned w3 = selv(rb1, selv(rb0, s0, r4), selv(rb0, r8, r12));
        aF[ks] = __builtin_bit_cast(short8, make_uint4(w0, w1, w2, w3));
    }

    // ---------------- stage nt=0 into buffer 0 ----------------
    {
        const char* src = (const char*)wB;
        #pragma unroll
        for (int g = 0; g < 2; ++g) {
            const int chunk = wave * 2 + g;
            __builtin_amdgcn_global_load_lds(
                (const __attribute__((address_space(1))) void*)(src + chunk * 1024 + lane * 16),
                (__attribute__((address_space(3))) void*)&S[chunk * 64 + lane], 16, 0, 0);
        }
    }
    __syncthreads();

    float u0[4] = {0,0,0,0}, u1[4] = {0,0,0,0}, u2[4] = {0,0,0,0}, u3[4] = {0,0,0,0};
    const int col = lane & 15;
    const int q   = lane >> 4;            // output quadrant: 0=h_hi,1=h_lo,2=ta,3=tb
    const bool qb0 = (q & 1) != 0;
    const bool qb1 = (q & 2) != 0;
    const bool qlt2 = (q < 2);

    #pragma unroll 1
    for (int nt = 0; nt < 16; ++nt) {
        // prefetch nt+1 into the other buffer (wraps harmlessly at nt=15)
        {
            const int ntn = (nt + 1) & 15;
            const int bn  = (nt + 1) & 1;
            const char* src = (const char*)wB + ntn * 16384;
            #pragma unroll
            for (int g = 0; g < 2; ++g) {
                const int chunk = wave * 2 + g;
                __builtin_amdgcn_global_load_lds(
                    (const __attribute__((address_space(1))) void*)(src + chunk * 1024 + lane * 16),
                    (__attribute__((address_space(3))) void*)&S[bn * 1024 + chunk * 64 + lane],
                    16, 0, 0);
            }
        }

        const int ncol = nt * 16 + col;
        const float4 hw  = hwp[ncol];
        const float  b1v = b1[ncol];

        const uint4* Bb = &S[(nt & 1) * 1024];
        f32x4 c1 = {0.f,0.f,0.f,0.f};   // A x W_hi
        f32x4 c2 = {0.f,0.f,0.f,0.f};   // A x W_lo
        #pragma unroll
        for (int ks = 0; ks < 8; ++ks) {
            const short8 bh = *reinterpret_cast<const short8*>(&Bb[ks * 64 + lane]);
            const short8 bl = *reinterpret_cast<const short8*>(&Bb[512 + ks * 64 + lane]);
            c1 = __builtin_amdgcn_mfma_f32_16x16x32_bf16(aF[ks], bh, c1, 0, 0, 0);
            c2 = __builtin_amdgcn_mfma_f32_16x16x32_bf16(aF[ks], bl, c2, 0, 0, 0);
        }

        // ---- epilogue: quadrant-dedup'd tanh (1 per lane per nt) ----
        float zs[4], zf[4], zA[4];
        #pragma unroll
        for (int r = 0; r < 4; ++r) zs[r] = c1[r] + c2[r];
        #pragma unroll
        for (int r = 0; r < 4; ++r) zf[r] = zs[r] + __shfl_xor(zs[r], 16) + b1v;
        #pragma unroll
        for (int r = 0; r < 4; ++r) {
            const float zr = __shfl_xor(zf[r], 32);
            zA[r] = qlt2 ? zf[r] : zr;
        }
        const float zpick = qb1 ? (qb0 ? zA[3] : zA[2]) : (qb0 ? zA[1] : zA[0]);
        const float hq = tanhf(zpick);
        const float g1 = __shfl_xor(hq, 16);
        const float g2 = __shfl_xor(hq, 32);
        const float g3 = __shfl_xor(hq, 48);
        float hr[4];
        hr[0] = qb1 ? (qb0 ? g3 : g2) : (qb0 ? g1 : hq);
        hr[1] = qb1 ? (qb0 ? g2 : g3) : (qb0 ? hq : g1);
        hr[2] = qb1 ? (qb0 ? g1 : hq) : (qb0 ? g3 : g2);
        hr[3] = qb1 ? (qb0 ? hq : g1) : (qb0 ? g2 : g3);
        #pragma unroll
        for (int r = 0; r < 4; ++r) {
            const float dt  = fmaf(-hr[r], hr[r], 1.f);
            const float val = qlt2 ? hr[r] : dt * zs[r];
            u0[r] = fmaf(val, hw.x, u0[r]);
            u1[r] = fmaf(val, hw.y, u1[r]);
            u2[r] = fmaf(val, hw.z, u2[r]);
            u3[r] = fmaf(val, hw.w, u3[r]);
        }
        __syncthreads();
    }

    // ---------------- column reduction across the 16 cols ----------------
    #pragma unroll
    for (int r = 0; r < 4; ++r) {
        #pragma unroll
        for (int m = 1; m < 16; m <<= 1) {
            u0[r] += __shfl_xor(u0[r], m);
            u1[r] += __shfl_xor(u1[r], m);
            u2[r] += __shfl_xor(u2[r], m);
            u3[r] += __shfl_xor(u3[r], m);
        }
    }
    // gather tangent sums onto q0: pa from q2 (xor32), pb from q3 (xor48)
    float pa0[4], pa1[4], pa2[4], pa3[4], pb0[4], pb1[4], pb2[4], pb3[4];
    #pragma unroll
    for (int r = 0; r < 4; ++r) {
        pa0[r] = __shfl_xor(u0[r], 32);
        pa1[r] = __shfl_xor(u1[r], 32);
        pa2[r] = __shfl_xor(u2[r], 32);
        pa3[r] = __shfl_xor(u3[r], 32);
        pb0[r] = __shfl_xor(u0[r], 48);
        pb1[r] = __shfl_xor(u1[r], 48);
        pb2[r] = __shfl_xor(u2[r], 48);
        pb3[r] = __shfl_xor(u3[r], 48);
    }

    if (lane == 0) {
        const float bd0 = bd[0], bd1 = bd[1], bo0 = bo[0];
        #pragma unroll
        for (int r = 0; r < 4; ++r) {
            const int sg = blockIdx.x * SB + wave * 4 + r;
            if (sg < n) {
                const float u    = x[sg * 6 + 2];
                const float vv   = x[sg * 6 + 3];
                const float tau0 = x[sg * 6 + 4];
                const float tau1 = x[sg * 6 + 5];

                const float zd0 = u0[r] + bd0;
                const float zd1 = u1[r] + bd1;
                const float zo  = u2[r] + bo0;

                const float ld0 = softplus_f(zd0) + 1e-4f;
                const float ld1 = softplus_f(zd1) + 1e-4f;
                const float lo  = zo;

                const float sg0 = 1.f / (1.f + expf(-zd0));
                const float sg1 = 1.f / (1.f + expf(-zd1));

                const float pa_d0 = pa0[r], pa_d1 = pa1[r], pa_o = pa2[r], pa_v = pa3[r];
                const float pb_d0 = pb0[r], pb_d1 = pb1[r], pb_o = pb2[r], pb_v = pb3[r];

                const float ld0a = sg0 * pa_d0, ld0b = sg0 * pb_d0;
                const float ld1a = sg1 * pa_d1, ld1b = sg1 * pb_d1;
                const float loa  = pa_o,        lob  = pb_o;
                const float ga   = pa_v,        gb   = pb_v;

                const float H00 = fmaf(ld0, ld0, 1e-4f);
                const float H01 = ld0 * lo;
                const float H11 = fmaf(lo, lo, fmaf(ld1, ld1, 1e-4f));

                const float dH00a = 2.f * ld0 * ld0a, dH00b = 2.f * ld0 * ld0b;
                const float dH01a = fmaf(ld0a, lo, ld0 * loa);
                const float dH01b = fmaf(ld0b, lo, ld0 * lob);
                const float dH11a = 2.f * fmaf(lo, loa, ld1 * ld1a);
                const float dH11b = 2.f * fmaf(lo, lob, ld1 * ld1b);

                const float wa0 = fmaf(dH00a, u, dH01a * vv);
                const float wa1 = fmaf(dH01a, u, dH11a * vv);
                const float wb0 = fmaf(dH00b, u, dH01b * vv);
                const float wb1 = fmaf(dH01b, u, dH11b * vv);

                const float QFa = dH00a*u*u + 2.f*dH01a*u*vv + dH11a*vv*vv;
                const float QFb = dH00b*u*u + 2.f*dH01b*u*vv + dH11b*vv*vv;

                const float C0 = fmaf(wa0, u, wb0 * vv) - 0.5f * QFa;
                const float C1 = fmaf(wa1, u, wb1 * vv) - 0.5f * QFb;

                const float r0 = tau0 - C0 - ga;
                const float r1 = tau1 - C1 - gb;

                const float det = fmaf(H00, H11, -H01 * H01);
                const float inv = 1.f / det;
                const float qdd0 = (H11 * r0 - H01 * r1) * inv;
                const float qdd1 = (H00 * r1 - H01 * r0) * inv;

                float2* o = reinterpret_cast<float2*>(&out[sg * 6]);
                o[0] = make_float2(u, vv);
                o[1] = make_float2(qdd0, qdd1);
                o[2] = make_float2(0.f, 0.f);
            }
        }
    }
}

extern "C" void kernel_launch(void* const* d_in, const int* in_sizes, int n_in,
                              void* d_out, int out_size, void* d_ws, size_t ws_size,
                              hipStream_t stream) {
    // dict order: t, x, W0, b0, W1, b1, Wd, bd, Wo, bo, Wv, bv
    const float* x  = (const float*)d_in[1];
    const float* W0 = (const float*)d_in[2];
    const float* b0 = (const float*)d_in[3];
    const float* W1 = (const float*)d_in[4];
    const float* b1 = (const float*)d_in[5];
    const float* Wd = (const float*)d_in[6];
    const float* bd = (const float*)d_in[7];
    const float* Wo = (const float*)d_in[8];
    const float* bo = (const float*)d_in[9];
    const float* Wv = (const float*)d_in[10];
    float* out = (float*)d_out;

    unsigned short* wB = (unsigned short*)d_ws;                         // 256 KB
    float4* w0p = (float4*)((char*)d_ws + 262144);                      // 4 KB
    float4* hwp = (float4*)((char*)d_ws + 262144 + 4096);               // 4 KB

    const int n = in_sizes[1] / 6;

    prep<<<32, 256, 0, stream>>>(W1, W0, Wd, Wo, Wv, wB, w0p, hwp);

    const int grid = (n + SB - 1) / SB;
    lode_mfma<<<grid, NTHREADS, 0, stream>>>(x, w0p, b0, wB, b1, hwp, bd, bo, out, n);
}

// Round 9
// 278.545 us; speedup vs baseline: 2.3472x; 1.0636x over previous
//
#include <hip/hip_runtime.h>
#include <math.h>

#define SB 32          // samples per block (4 per wave, 8 waves)
#define NTHREADS 512

typedef short short8 __attribute__((ext_vector_type(8)));
typedef float f32x4  __attribute__((ext_vector_type(4)));

__device__ __forceinline__ unsigned short f2bf(float f) {
    unsigned int u = __builtin_bit_cast(unsigned int, f);
    unsigned int r = (u + 0x7FFFu + ((u >> 16) & 1u)) >> 16;   // RNE
    return (unsigned short)r;
}
__device__ __forceinline__ float bf2f(unsigned short h) {
    unsigned int u = ((unsigned int)h) << 16;
    return __builtin_bit_cast(float, u);
}
__device__ __forceinline__ unsigned pack2(unsigned short lo, unsigned short hi) {
    return (unsigned)lo | ((unsigned)hi << 16);
}
__device__ __forceinline__ float softplus_f(float z) {
    return z > 15.f ? z : log1pf(expf(z));
}
__device__ __forceinline__ float fast_tanh(float z) {
    // tanh(z) = 1 - 2/(exp(2z)+1); exp2-based, ~2e-7 abs err
    const float e = __builtin_amdgcn_exp2f(z * 2.8853900817779268f);
    return fmaf(-2.f, __builtin_amdgcn_rcpf(e + 1.f), 1.f);
}
__device__ __forceinline__ unsigned selv(bool c, unsigned a, unsigned b) {
    return c ? a : b;
}
__device__ __forceinline__ unsigned sx(unsigned v, int m) {
    return (unsigned)__shfl_xor((int)v, m);
}

// ---------------- prep: pack W1 (split hi/lo) + W0 + head weights ----------------
__global__ void prep(const float* __restrict__ W1, const float* __restrict__ W0,
                     const float* __restrict__ Wd, const float* __restrict__ Wo,
                     const float* __restrict__ Wv,
                     unsigned short* __restrict__ wB,
                     float4* __restrict__ w0p, float4* __restrict__ hwp)
{
    int idx = blockIdx.x * blockDim.x + threadIdx.x;
    if (idx < 256) {
        w0p[idx] = make_float4(W0[idx], W0[256 + idx], W0[512 + idx], W0[768 + idx]);
        hwp[idx] = make_float4(Wd[2 * idx], Wd[2 * idx + 1], Wo[idx], Wv[idx]);
    }
    if (idx < 8192) {
        const int l  = idx & 63;
        const int ks = (idx >> 6) & 7;
        const int nt = idx >> 9;
        const int k0 = ks * 32 + (l >> 4) * 8;
        const int n  = nt * 16 + (l & 15);
        const int hbase = (nt * 1024 + ks * 64 + l) * 8;
        const int lbase = (nt * 1024 + 512 + ks * 64 + l) * 8;
        #pragma unroll
        for (int i = 0; i < 8; ++i) {
            const float f = W1[(k0 + i) * 256 + n];
            const unsigned short hi = f2bf(f);
            const unsigned short lo = f2bf(f - bf2f(hi));
            wB[hbase + i] = hi;
            wB[lbase + i] = lo;
        }
    }
}

// A rows (16): row = rho*4 + s ; rho: 0=h_hi, 1=h_lo, 2=ta, 3=tb ; s = sample 0..3.
// Lane l: r15=l&15 -> (rho=r15>>2, s=r15&3), kg=l>>4; element i -> k=ks*32+kg*8+i.
// Phase-1 dedupe: lane computes neurons j = ks*32+kg*8+2*rho+{0,1} for sample s
// (2 tanh instead of 8) and produces ALL four pack types; a 4-lane shuffle
// transpose (xor 4/8/12) then gives each lane its own row-type for all 4 pairs.
__global__ __launch_bounds__(NTHREADS, 4)
void lode_mfma(const float* __restrict__ x,
               const float4* __restrict__ w0p, const float* __restrict__ b0,
               const unsigned short* __restrict__ wB,
               const float* __restrict__ b1,
               const float4* __restrict__ hwp,
               const float* __restrict__ bd, const float* __restrict__ bo,
               float* __restrict__ out, int n)
{
    __shared__ uint4 S[2048];   // 32 KB B double-buffer

    const int tid  = threadIdx.x;
    const int wave = tid >> 6;
    const int lane = tid & 63;
    const int r15  = lane & 15;
    const int s    = r15 & 3;
    const int rho  = r15 >> 2;
    const bool rb0 = (rho & 1) != 0;
    const bool rb1 = (rho & 2) != 0;

    // ---------------- phase 1: in-register A fragments ----------------
    int sg1 = blockIdx.x * SB + wave * 4 + s;
    if (sg1 >= n) sg1 = n - 1;
    const float qq0 = x[sg1 * 6 + 0];
    const float qq1 = x[sg1 * 6 + 1];
    // sincos dedupe: even rho computes q0's pair, odd rho computes q1's; exchange xor4
    float ss_, cc_;
    sincosf(rb0 ? qq1 : qq0, &ss_, &cc_);
    const float ss_o = __shfl_xor(ss_, 4);
    const float cc_o = __shfl_xor(cc_, 4);
    const float sn0 = rb0 ? ss_o : ss_;
    const float cs0 = rb0 ? cc_o : cc_;
    const float sn1 = rb0 ? ss_ : ss_o;
    const float cs1 = rb0 ? cc_ : cc_o;

    short8 aF[8];
    #pragma unroll
    for (int ks = 0; ks < 8; ++ks) {
        const int kg = lane >> 4;
        const int j0 = ks * 32 + kg * 8 + 2 * rho;
        const float4 wa = w0p[j0];
        const float4 wb = w0p[j0 + 1];
        const float2 bb = *reinterpret_cast<const float2*>(&b0[j0]);
        float z0 = bb.x;
        z0 = fmaf(cs0, wa.x, z0); z0 = fmaf(cs1, wa.y, z0);
        z0 = fmaf(sn0, wa.z, z0); z0 = fmaf(sn1, wa.w, z0);
        float z1 = bb.y;
        z1 = fmaf(cs0, wb.x, z1); z1 = fmaf(cs1, wb.y, z1);
        z1 = fmaf(sn0, wb.z, z1); z1 = fmaf(sn1, wb.w, z1);
        const float h0 = fast_tanh(z0);
        const float h1 = fast_tanh(z1);
        const unsigned short h0h = f2bf(h0);
        const unsigned short h1h = f2bf(h1);
        const unsigned short h0l = f2bf(h0 - bf2f(h0h));
        const unsigned short h1l = f2bf(h1 - bf2f(h1h));
        const float dt0 = fmaf(-h0, h0, 1.f);
        const float dt1 = fmaf(-h1, h1, 1.f);
        const float ta0 = dt0 * fmaf(-sn0, wa.x, cs0 * wa.z);
        const float ta1 = dt1 * fmaf(-sn0, wb.x, cs0 * wb.z);
        const float tb0 = dt0 * fmaf(-sn1, wa.y, cs1 * wa.w);
        const float tb1 = dt1 * fmaf(-sn1, wb.y, cs1 * wb.w);
        const unsigned v0 = pack2(h0h, h1h);                       // type 0: h_hi
        const unsigned v1 = pack2(h0l, h1l);                       // type 1: h_lo
        const unsigned v2 = pack2(f2bf(ta0), f2bf(ta1));           // type 2: ta
        const unsigned v3 = pack2(f2bf(tb0), f2bf(tb1));           // type 3: tb
        // gather v[rho^k] via selects, exchange via xor 4/8/12
        const unsigned s0 = selv(rb1, selv(rb0, v3, v2), selv(rb0, v1, v0)); // v[rho]
        const unsigned s1 = selv(rb1, selv(rb0, v2, v3), selv(rb0, v0, v1)); // v[rho^1]
        const unsigned s2 = selv(rb1, selv(rb0, v1, v0), selv(rb0, v3, v2)); // v[rho^2]
        const unsigned s3 = selv(rb1, selv(rb0, v0, v1), selv(rb0, v2, v3)); // v[rho^3]
        const unsigned r4  = sx(s1, 4);
        const unsigned r8  = sx(s2, 8);
        const unsigned r12 = sx(s3, 12);
        // w[p]: own-type pack for pair p
        const unsigned w0 = selv(rb1, selv(rb0, r12, r8), selv(rb0, r4, s0));
        const unsigned w1 = selv(rb1, selv(rb0, r8, r12), selv(rb0, s0, r4));
        const unsigned w2 = selv(rb1, selv(rb0, r4, s0), selv(rb0, r12, r8));
        const unsigned w3 = selv(rb1, selv(rb0, s0, r4), selv(rb0, r8, r12));
        aF[ks] = __builtin_bit_cast(short8, make_uint4(w0, w1, w2, w3));
    }

    // ---------------- stage nt=0 into buffer 0 ----------------
    {
        const char* src = (const char*)wB;
        #pragma unroll
        for (int g = 0; g < 2; ++g) {
            const int chunk = wave * 2 + g;
            __builtin_amdgcn_global_load_lds(
                (const __attribute__((address_space(1))) void*)(src + chunk * 1024 + lane * 16),
                (__attribute__((address_space(3))) void*)&S[chunk * 64 + lane], 16, 0, 0);
        }
    }
    __syncthreads();

    float u0[4] = {0,0,0,0}, u1[4] = {0,0,0,0}, u2[4] = {0,0,0,0}, u3[4] = {0,0,0,0};
    const int col = lane & 15;
    const int q   = lane >> 4;            // output quadrant: 0=h_hi,1=h_lo,2=ta,3=tb
    const bool qb0 = (q & 1) != 0;
    const bool qb1 = (q & 2) != 0;
    const bool qlt2 = (q < 2);

    #pragma unroll 1
    for (int nt = 0; nt < 16; ++nt) {
        // prefetch nt+1 into the other buffer (wraps harmlessly at nt=15)
        {
            const int ntn = (nt + 1) & 15;
            const int bn  = (nt + 1) & 1;
            const char* src = (const char*)wB + ntn * 16384;
            #pragma unroll
            for (int g = 0; g < 2; ++g) {
                const int chunk = wave * 2 + g;
                __builtin_amdgcn_global_load_lds(
                    (const __attribute__((address_space(1))) void*)(src + chunk * 1024 + lane * 16),
                    (__attribute__((address_space(3))) void*)&S[bn * 1024 + chunk * 64 + lane],
                    16, 0, 0);
            }
        }

        const int ncol = nt * 16 + col;
        const float4 hw  = hwp[ncol];
        const float  b1v = b1[ncol];

        const uint4* Bb = &S[(nt & 1) * 1024];
        f32x4 c1 = {0.f,0.f,0.f,0.f};   // A x W_hi
        f32x4 c2 = {0.f,0.f,0.f,0.f};   // A x W_lo
        #pragma unroll
        for (int ks = 0; ks < 8; ++ks) {
            const short8 bh = *reinterpret_cast<const short8*>(&Bb[ks * 64 + lane]);
            const short8 bl = *reinterpret_cast<const short8*>(&Bb[512 + ks * 64 + lane]);
            c1 = __builtin_amdgcn_mfma_f32_16x16x32_bf16(aF[ks], bh, c1, 0, 0, 0);
            c2 = __builtin_amdgcn_mfma_f32_16x16x32_bf16(aF[ks], bl, c2, 0, 0, 0);
        }

        // ---- epilogue: quadrant-dedup'd tanh (1 per lane per nt) ----
        float zs[4], zf[4], zA[4];
        #pragma unroll
        for (int r = 0; r < 4; ++r) zs[r] = c1[r] + c2[r];
        #pragma unroll
        for (int r = 0; r < 4; ++r) zf[r] = zs[r] + __shfl_xor(zs[r], 16) + b1v;
        #pragma unroll
        for (int r = 0; r < 4; ++r) {
            const float zr = __shfl_xor(zf[r], 32);
            zA[r] = qlt2 ? zf[r] : zr;
        }
        const float zpick = qb1 ? (qb0 ? zA[3] : zA[2]) : (qb0 ? zA[1] : zA[0]);
        const float hq = fast_tanh(zpick);
        const float g1 = __shfl_xor(hq, 16);
        const float g2 = __shfl_xor(hq, 32);
        const float g3 = __shfl_xor(hq, 48);
        float hr[4];
        hr[0] = qb1 ? (qb0 ? g3 : g2) : (qb0 ? g1 : hq);
        hr[1] = qb1 ? (qb0 ? g2 : g3) : (qb0 ? hq : g1);
        hr[2] = qb1 ? (qb0 ? g1 : hq) : (qb0 ? g3 : g2);
        hr[3] = qb1 ? (qb0 ? hq : g1) : (qb0 ? g2 : g3);
        #pragma unroll
        for (int r = 0; r < 4; ++r) {
            const float dt  = fmaf(-hr[r], hr[r], 1.f);
            const float val = qlt2 ? hr[r] : dt * zs[r];
            u0[r] = fmaf(val, hw.x, u0[r]);
            u1[r] = fmaf(val, hw.y, u1[r]);
            u2[r] = fmaf(val, hw.z, u2[r]);
            u3[r] = fmaf(val, hw.w, u3[r]);
        }
        __syncthreads();
    }

    // ---------------- column reduction across the 16 cols ----------------
    #pragma unroll
    for (int r = 0; r < 4; ++r) {
        #pragma unroll
        for (int m = 1; m < 16; m <<= 1) {
            u0[r] += __shfl_xor(u0[r], m);
            u1[r] += __shfl_xor(u1[r], m);
            u2[r] += __shfl_xor(u2[r], m);
            u3[r] += __shfl_xor(u3[r], m);
        }
    }
    // gather tangent sums onto q0: pa from q2 (xor32), pb from q3 (xor48)
    float pa0[4], pa1[4], pa2[4], pa3[4], pb0[4], pb1[4], pb2[4], pb3[4];
    #pragma unroll
    for (int r = 0; r < 4; ++r) {
        pa0[r] = __shfl_xor(u0[r], 32);
        pa1[r] = __shfl_xor(u1[r], 32);
        pa2[r] = __shfl_xor(u2[r], 32);
        pa3[r] = __shfl_xor(u3[r], 32);
        pb0[r] = __shfl_xor(u0[r], 48);
        pb1[r] = __shfl_xor(u1[r], 48);
        pb2[r] = __shfl_xor(u2[r], 48);
        pb3[r] = __shfl_xor(u3[r], 48);
    }

    if (lane == 0) {
        const float bd0 = bd[0], bd1 = bd[1], bo0 = bo[0];
        #pragma unroll
        for (int r = 0; r < 4; ++r) {
            const int sg = blockIdx.x * SB + wave * 4 + r;
            if (sg < n) {
                const float u    = x[sg * 6 + 2];
                const float vv   = x[sg * 6 + 3];
                const float tau0 = x[sg * 6 + 4];
                const float tau1 = x[sg * 6 + 5];

                const float zd0 = u0[r] + bd0;
                const float zd1 = u1[r] + bd1;
                const float zo  = u2[r] + bo0;

                const float ld0 = softplus_f(zd0) + 1e-4f;
                const float ld1 = softplus_f(zd1) + 1e-4f;
                const float lo  = zo;

                const float sg0 = 1.f / (1.f + expf(-zd0));
                const float sg1 = 1.f / (1.f + expf(-zd1));

                const float pa_d0 = pa0[r], pa_d1 = pa1[r], pa_o = pa2[r], pa_v = pa3[r];
                const float pb_d0 = pb0[r], pb_d1 = pb1[r], pb_o = pb2[r], pb_v = pb3[r];

                const float ld0a = sg0 * pa_d0, ld0b = sg0 * pb_d0;
                const float ld1a = sg1 * pa_d1, ld1b = sg1 * pb_d1;
                const float loa  = pa_o,        lob  = pb_o;
                const float ga   = pa_v,        gb   = pb_v;

                const float H00 = fmaf(ld0, ld0, 1e-4f);
                const float H01 = ld0 * lo;
                const float H11 = fmaf(lo, lo, fmaf(ld1, ld1, 1e-4f));

                const float dH00a = 2.f * ld0 * ld0a, dH00b = 2.f * ld0 * ld0b;
                const float dH01a = fmaf(ld0a, lo, ld0 * loa);
                const float dH01b = fmaf(ld0b, lo, ld0 * lob);
                const float dH11a = 2.f * fmaf(lo, loa, ld1 * ld1a);
                const float dH11b = 2.f * fmaf(lo, lob, ld1 * ld1b);

                const float wa0 = fmaf(dH00a, u, dH01a * vv);
                const float wa1 = fmaf(dH01a, u, dH11a * vv);
                const float wb0 = fmaf(dH00b, u, dH01b * vv);
                const float wb1 = fmaf(dH01b, u, dH11b * vv);

                const float QFa = dH00a*u*u + 2.f*dH01a*u*vv + dH11a*vv*vv;
                const float QFb = dH00b*u*u + 2.f*dH01b*u*vv + dH11b*vv*vv;

                const float C0 = fmaf(wa0, u, wb0 * vv) - 0.5f * QFa;
                const float C1 = fmaf(wa1, u, wb1 * vv) - 0.5f * QFb;

                const float r0 = tau0 - C0 - ga;
                const float r1 = tau1 - C1 - gb;

                const float det = fmaf(H00, H11, -H01 * H01);
                const float inv = 1.f / det;
                const float qdd0 = (H11 * r0 - H01 * r1) * inv;
                const float qdd1 = (H00 * r1 - H01 * r0) * inv;

                float2* o = reinterpret_cast<float2*>(&out[sg * 6]);
                o[0] = make_float2(u, vv);
                o[1] = make_float2(qdd0, qdd1);
                o[2] = make_float2(0.f, 0.f);
            }
        }
    }
}

extern "C" void kernel_launch(void* const* d_in, const int* in_sizes, int n_in,
                              void* d_out, int out_size, void* d_ws, size_t ws_size,
                              hipStream_t stream) {
    // dict order: t, x, W0, b0, W1, b1, Wd, bd, Wo, bo, Wv, bv
    const float* x  = (const float*)d_in[1];
    const float* W0 = (const float*)d_in[2];
    const float* b0 = (const float*)d_in[3];
    const float* W1 = (const float*)d_in[4];
    const float* b1 = (const float*)d_in[5];
    const float* Wd = (const float*)d_in[6];
    const float* bd = (const float*)d_in[7];
    const float* Wo = (const float*)d_in[8];
    const float* bo = (const float*)d_in[9];
    const float* Wv = (const float*)d_in[10];
    float* out = (float*)d_out;

    unsigned short* wB = (unsigned short*)d_ws;                         // 256 KB
    float4* w0p = (float4*)((char*)d_ws + 262144);                      // 4 KB
    float4* hwp = (float4*)((char*)d_ws + 262144 + 4096);               // 4 KB

    const int n = in_sizes[1] / 6;

    prep<<<32, 256, 0, stream>>>(W1, W0, Wd, Wo, Wv, wB, w0p, hwp);

    const int grid = (n + SB - 1) / SB;
    lode_mfma<<<grid, NTHREADS, 0, stream>>>(x, w0p, b0, wB, b1, hwp, bd, bo, out, n);
}

// Round 11
// 278.436 us; speedup vs baseline: 2.3481x; 1.0004x over previous
//
#include <hip/hip_runtime.h>
#include <math.h>

#define SB 32          // samples per block (8 per wave, 4 waves)
#define NTHREADS 256

typedef short short8 __attribute__((ext_vector_type(8)));
typedef float f32x4  __attribute__((ext_vector_type(4)));

__device__ __forceinline__ unsigned short f2bf(float f) {
    unsigned int u = __builtin_bit_cast(unsigned int, f);
    unsigned int r = (u + 0x7FFFu + ((u >> 16) & 1u)) >> 16;   // RNE
    return (unsigned short)r;
}
__device__ __forceinline__ float bf2f(unsigned short h) {
    unsigned int u = ((unsigned int)h) << 16;
    return __builtin_bit_cast(float, u);
}
__device__ __forceinline__ unsigned pack2(unsigned short lo, unsigned short hi) {
    return (unsigned)lo | ((unsigned)hi << 16);
}
__device__ __forceinline__ float softplus_f(float z) {
    return z > 15.f ? z : log1pf(expf(z));
}
__device__ __forceinline__ float fast_tanh(float z) {
    const float e = __builtin_amdgcn_exp2f(z * 2.8853900817779268f);
    return fmaf(-2.f, __builtin_amdgcn_rcpf(e + 1.f), 1.f);
}
__device__ __forceinline__ unsigned selv(bool c, unsigned a, unsigned b) {
    return c ? a : b;
}
__device__ __forceinline__ unsigned sx(unsigned v, int m) {
    return (unsigned)__shfl_xor((int)v, m);
}

// ---------------- prep: pack W1 (split hi/lo) + W0 + head weights (r9 layout) ----
// wB (uint4 slots): nt*1024 + [hi: ks*64+l | lo: 512+ks*64+l]
// slot element i: B[k][n], k = ks*32 + (l>>4)*8 + i, n = nt*16 + (l&15)
__global__ void prep(const float* __restrict__ W1, const float* __restrict__ W0,
                     const float* __restrict__ Wd, const float* __restrict__ Wo,
                     const float* __restrict__ Wv,
                     unsigned short* __restrict__ wB,
                     float4* __restrict__ w0p, float4* __restrict__ hwp)
{
    int idx = blockIdx.x * blockDim.x + threadIdx.x;
    if (idx < 256) {
        w0p[idx] = make_float4(W0[idx], W0[256 + idx], W0[512 + idx], W0[768 + idx]);
        hwp[idx] = make_float4(Wd[2 * idx], Wd[2 * idx + 1], Wo[idx], Wv[idx]);
    }
    if (idx < 8192) {
        const int l  = idx & 63;
        const int ks = (idx >> 6) & 7;
        const int nt = idx >> 9;
        const int k0 = ks * 32 + (l >> 4) * 8;
        const int n  = nt * 16 + (l & 15);
        const int hbase = (nt * 1024 + ks * 64 + l) * 8;
        const int lbase = (nt * 1024 + 512 + ks * 64 + l) * 8;
        #pragma unroll
        for (int i = 0; i < 8; ++i) {
            const float f = W1[(k0 + i) * 256 + n];
            const unsigned short hi = f2bf(f);
            const unsigned short lo = f2bf(f - bf2f(hi));
            wB[hbase + i] = hi;
            wB[lbase + i] = lo;
        }
    }
}

// Build one 16-row A fragment set (rows = rho*4+s: h_hi,h_lo,ta,tb x 4 samples).
// Identical arithmetic + exchange (xor 4/8/12) to the r9-passing kernel.
__device__ __forceinline__ void build_aF(
    const float4* __restrict__ w0p, const float* __restrict__ b0,
    int kg, int rho, bool rb0, bool rb1,
    float sn0, float cs0, float sn1, float cs1, short8* aF)
{
    #pragma unroll
    for (int ks = 0; ks < 8; ++ks) {
        const int j0 = ks * 32 + kg * 8 + 2 * rho;
        const float4 wa = w0p[j0];
        const float4 wb = w0p[j0 + 1];
        const float2 bb = *reinterpret_cast<const float2*>(&b0[j0]);
        float z0 = bb.x;
        z0 = fmaf(cs0, wa.x, z0); z0 = fmaf(cs1, wa.y, z0);
        z0 = fmaf(sn0, wa.z, z0); z0 = fmaf(sn1, wa.w, z0);
        float z1 = bb.y;
        z1 = fmaf(cs0, wb.x, z1); z1 = fmaf(cs1, wb.y, z1);
        z1 = fmaf(sn0, wb.z, z1); z1 = fmaf(sn1, wb.w, z1);
        const float h0 = fast_tanh(z0);
        const float h1 = fast_tanh(z1);
        const unsigned short h0h = f2bf(h0);
        const unsigned short h1h = f2bf(h1);
        const unsigned short h0l = f2bf(h0 - bf2f(h0h));
        const unsigned short h1l = f2bf(h1 - bf2f(h1h));
        const float dt0 = fmaf(-h0, h0, 1.f);
        const float dt1 = fmaf(-h1, h1, 1.f);
        const float ta0 = dt0 * fmaf(-sn0, wa.x, cs0 * wa.z);
        const float ta1 = dt1 * fmaf(-sn0, wb.x, cs0 * wb.z);
        const float tb0 = dt0 * fmaf(-sn1, wa.y, cs1 * wa.w);
        const float tb1 = dt1 * fmaf(-sn1, wb.y, cs1 * wb.w);
        const unsigned v0 = pack2(h0h, h1h);
        const unsigned v1 = pack2(h0l, h1l);
        const unsigned v2 = pack2(f2bf(ta0), f2bf(ta1));
        const unsigned v3 = pack2(f2bf(tb0), f2bf(tb1));
        const unsigned s0 = selv(rb1, selv(rb0, v3, v2), selv(rb0, v1, v0));
        const unsigned s1 = selv(rb1, selv(rb0, v2, v3), selv(rb0, v0, v1));
        const unsigned s2 = selv(rb1, selv(rb0, v1, v0), selv(rb0, v3, v2));
        const unsigned s3 = selv(rb1, selv(rb0, v0, v1), selv(rb0, v2, v3));
        const unsigned r4  = sx(s1, 4);
        const unsigned r8  = sx(s2, 8);
        const unsigned r12 = sx(s3, 12);
        const unsigned w0 = selv(rb1, selv(rb0, r12, r8), selv(rb0, r4, s0));
        const unsigned w1 = selv(rb1, selv(rb0, r8, r12), selv(rb0, s0, r4));
        const unsigned w2 = selv(rb1, selv(rb0, r4, s0), selv(rb0, r12, r8));
        const unsigned w3 = selv(rb1, selv(rb0, s0, r4), selv(rb0, r8, r12));
        aF[ks] = __builtin_bit_cast(short8, make_uint4(w0, w1, w2, w3));
    }
}

// r9's quadrant-dedup'd epilogue accumulation (1 tanh/lane/call).
__device__ __forceinline__ void epi_acc(
    const f32x4& c1, const f32x4& c2, float b1v, const float4& hw,
    bool qb0, bool qb1, bool qlt2,
    float* u0, float* u1, float* u2, float* u3)
{
    float zs[4], zf[4], zA[4];
    #pragma unroll
    for (int r = 0; r < 4; ++r) zs[r] = c1[r] + c2[r];
    #pragma unroll
    for (int r = 0; r < 4; ++r) zf[r] = zs[r] + __shfl_xor(zs[r], 16) + b1v;
    #pragma unroll
    for (int r = 0; r < 4; ++r) {
        const float zr = __shfl_xor(zf[r], 32);
        zA[r] = qlt2 ? zf[r] : zr;
    }
    const float zpick = qb1 ? (qb0 ? zA[3] : zA[2]) : (qb0 ? zA[1] : zA[0]);
    const float hq = fast_tanh(zpick);
    const float g1 = __shfl_xor(hq, 16);
    const float g2 = __shfl_xor(hq, 32);
    const float g3 = __shfl_xor(hq, 48);
    float hr[4];
    hr[0] = qb1 ? (qb0 ? g3 : g2) : (qb0 ? g1 : hq);
    hr[1] = qb1 ? (qb0 ? g2 : g3) : (qb0 ? hq : g1);
    hr[2] = qb1 ? (qb0 ? g1 : hq) : (qb0 ? g3 : g2);
    hr[3] = qb1 ? (qb0 ? hq : g1) : (qb0 ? g2 : g3);
    #pragma unroll
    for (int r = 0; r < 4; ++r) {
        const float dt  = fmaf(-hr[r], hr[r], 1.f);
        const float val = qlt2 ? hr[r] : dt * zs[r];
        u0[r] = fmaf(val, hw.x, u0[r]);
        u1[r] = fmaf(val, hw.y, u1[r]);
        u2[r] = fmaf(val, hw.z, u2[r]);
        u3[r] = fmaf(val, hw.w, u3[r]);
    }
}

// scalar per-sample dynamics solve + output write (r9 body)
__device__ __forceinline__ void solve_write(
    const float* __restrict__ x, float* __restrict__ out, int sg,
    float phd0, float phd1, float phoo,
    float pad0, float pad1, float pao, float pav,
    float pbd0, float pbd1, float pbo, float pbv,
    float bd0, float bd1, float bo0)
{
    const float u    = x[sg * 6 + 2];
    const float vv   = x[sg * 6 + 3];
    const float tau0 = x[sg * 6 + 4];
    const float tau1 = x[sg * 6 + 5];

    const float zd0 = phd0 + bd0;
    const float zd1 = phd1 + bd1;
    const float zo  = phoo + bo0;

    const float ld0 = softplus_f(zd0) + 1e-4f;
    const float ld1 = softplus_f(zd1) + 1e-4f;
    const float lo  = zo;

    const float sg0 = 1.f / (1.f + expf(-zd0));
    const float sg1 = 1.f / (1.f + expf(-zd1));

    const float ld0a = sg0 * pad0, ld0b = sg0 * pbd0;
    const float ld1a = sg1 * pad1, ld1b = sg1 * pbd1;
    const float loa  = pao,        lob  = pbo;
    const float ga   = pav,        gb   = pbv;

    const float H00 = fmaf(ld0, ld0, 1e-4f);
    const float H01 = ld0 * lo;
    const float H11 = fmaf(lo, lo, fmaf(ld1, ld1, 1e-4f));

    const float dH00a = 2.f * ld0 * ld0a, dH00b = 2.f * ld0 * ld0b;
    const float dH01a = fmaf(ld0a, lo, ld0 * loa);
    const float dH01b = fmaf(ld0b, lo, ld0 * lob);
    const float dH11a = 2.f * fmaf(lo, loa, ld1 * ld1a);
    const float dH11b = 2.f * fmaf(lo, lob, ld1 * ld1b);

    const float wa0 = fmaf(dH00a, u, dH01a * vv);
    const float wa1 = fmaf(dH01a, u, dH11a * vv);
    const float wb0 = fmaf(dH00b, u, dH01b * vv);
    const float wb1 = fmaf(dH01b, u, dH11b * vv);

    const float QFa = dH00a*u*u + 2.f*dH01a*u*vv + dH11a*vv*vv;
    const float QFb = dH00b*u*u + 2.f*dH01b*u*vv + dH11b*vv*vv;

    const float C0 = fmaf(wa0, u, wb0 * vv) - 0.5f * QFa;
    const float C1 = fmaf(wa1, u, wb1 * vv) - 0.5f * QFb;

    const float r0 = tau0 - C0 - ga;
    const float r1 = tau1 - C1 - gb;

    const float det = fmaf(H00, H11, -H01 * H01);
    const float inv = 1.f / det;
    const float qdd0 = (H11 * r0 - H01 * r1) * inv;
    const float qdd1 = (H00 * r1 - H01 * r0) * inv;

    float2* o = reinterpret_cast<float2*>(&out[sg * 6]);
    o[0] = make_float2(u, vv);
    o[1] = make_float2(qdd0, qdd1);
    o[2] = make_float2(0.f, 0.f);
}

__global__ __launch_bounds__(NTHREADS, 3)
void lode_mfma(const float* __restrict__ x,
               const float4* __restrict__ w0p, const float* __restrict__ b0,
               const unsigned short* __restrict__ wB,
               const float* __restrict__ b1,
               const float4* __restrict__ hwp,
               const float* __restrict__ bd, const float* __restrict__ bo,
               float* __restrict__ out, int n)
{
    __shared__ uint4 S[2048];   // 32 KB B double-buffer

    const int tid  = threadIdx.x;
    const int wave = tid >> 6;
    const int lane = tid & 63;
    const int r15  = lane & 15;
    const int s    = r15 & 3;
    const int rho  = r15 >> 2;
    const bool rb0 = (rho & 1) != 0;
    const bool rb1 = (rho & 2) != 0;
    const int kg   = lane >> 4;

    // ---------------- phase 1: two A-fragment sets (samples wave*8+s / +4+s) ----
    int sgA = blockIdx.x * SB + wave * 8 + s;
    int sgB = sgA + 4;
    if (sgA >= n) sgA = n - 1;
    if (sgB >= n) sgB = n - 1;
    const float qA0 = x[sgA * 6 + 0];
    const float qA1 = x[sgA * 6 + 1];
    const float qB0 = x[sgB * 6 + 0];
    const float qB1 = x[sgB * 6 + 1];
    float ssA, ccA, ssB, ccB;
    sincosf(rb0 ? qA1 : qA0, &ssA, &ccA);
    sincosf(rb0 ? qB1 : qB0, &ssB, &ccB);
    const float ssAo = __shfl_xor(ssA, 4), ccAo = __shfl_xor(ccA, 4);
    const float ssBo = __shfl_xor(ssB, 4), ccBo = __shfl_xor(ccB, 4);
    const float snA0 = rb0 ? ssAo : ssA, csA0 = rb0 ? ccAo : ccA;
    const float snA1 = rb0 ? ssA : ssAo, csA1 = rb0 ? ccA : ccAo;
    const float snB0 = rb0 ? ssBo : ssB, csB0 = rb0 ? ccBo : ccB;
    const float snB1 = rb0 ? ssB : ssBo, csB1 = rb0 ? ccB : ccBo;

    short8 aFA[8], aFB[8];
    build_aF(w0p, b0, kg, rho, rb0, rb1, snA0, csA0, snA1, csA1, aFA);
    build_aF(w0p, b0, kg, rho, rb0, rb1, snB0, csB0, snB1, csB1, aFB);

    // ---------------- stage nt=0 into buffer 0 (r7 4-wave pattern) ----------------
    {
        const char* src = (const char*)wB;
        #pragma unroll
        for (int g = 0; g < 4; ++g) {
            const int chunk = g * 4 + wave;
            __builtin_amdgcn_global_load_lds(
                (const __attribute__((address_space(1))) void*)(src + chunk * 1024 + lane * 16),
                (__attribute__((address_space(3))) void*)&S[chunk * 64 + lane], 16, 0, 0);
        }
    }
    __syncthreads();

    float uA0[4] = {0,0,0,0}, uA1[4] = {0,0,0,0}, uA2[4] = {0,0,0,0}, uA3[4] = {0,0,0,0};
    float uB0[4] = {0,0,0,0}, uB1[4] = {0,0,0,0}, uB2[4] = {0,0,0,0}, uB3[4] = {0,0,0,0};
    const int col = lane & 15;
    const int q   = lane >> 4;
    const bool qb0 = (q & 1) != 0;
    const bool qb1 = (q & 2) != 0;
    const bool qlt2 = (q < 2);

    #pragma unroll 1
    for (int nt = 0; nt < 16; ++nt) {
        // prefetch nt+1 into the other buffer (wraps harmlessly at nt=15)
        {
            const int ntn = (nt + 1) & 15;
            const int bn  = (nt + 1) & 1;
            const char* src = (const char*)wB + ntn * 16384;
            #pragma unroll
            for (int g = 0; g < 4; ++g) {
                const int chunk = g * 4 + wave;
                __builtin_amdgcn_global_load_lds(
                    (const __attribute__((address_space(1))) void*)(src + chunk * 1024 + lane * 16),
                    (__attribute__((address_space(3))) void*)&S[bn * 1024 + chunk * 64 + lane],
                    16, 0, 0);
            }
        }

        const int ncol = nt * 16 + col;
        const float4 hw  = hwp[ncol];
        const float  b1v = b1[ncol];

        const uint4* Bb = &S[(nt & 1) * 1024];
        f32x4 c1A = {0.f,0.f,0.f,0.f}, c2A = {0.f,0.f,0.f,0.f};
        f32x4 c1B = {0.f,0.f,0.f,0.f}, c2B = {0.f,0.f,0.f,0.f};
        #pragma unroll
        for (int ks = 0; ks < 8; ++ks) {
            const short8 bh = *reinterpret_cast<const short8*>(&Bb[ks * 64 + lane]);
            const short8 bl = *reinterpret_cast<const short8*>(&Bb[512 + ks * 64 + lane]);
            c1A = __builtin_amdgcn_mfma_f32_16x16x32_bf16(aFA[ks], bh, c1A, 0, 0, 0);
            c2A = __builtin_amdgcn_mfma_f32_16x16x32_bf16(aFA[ks], bl, c2A, 0, 0, 0);
            c1B = __builtin_amdgcn_mfma_f32_16x16x32_bf16(aFB[ks], bh, c1B, 0, 0, 0);
            c2B = __builtin_amdgcn_mfma_f32_16x16x32_bf16(aFB[ks], bl, c2B, 0, 0, 0);
        }

        epi_acc(c1A, c2A, b1v, hw, qb0, qb1, qlt2, uA0, uA1, uA2, uA3);
        epi_acc(c1B, c2B, b1v, hw, qb0, qb1, qlt2, uB0, uB1, uB2, uB3);
        __syncthreads();
    }

    // ---------------- column reduction across the 16 cols ----------------
    #pragma unroll
    for (int r = 0; r < 4; ++r) {
        #pragma unroll
        for (int m = 1; m < 16; m <<= 1) {
            uA0[r] += __shfl_xor(uA0[r], m);
            uA1[r] += __shfl_xor(uA1[r], m);
            uA2[r] += __shfl_xor(uA2[r], m);
            uA3[r] += __shfl_xor(uA3[r], m);
            uB0[r] += __shfl_xor(uB0[r], m);
            uB1[r] += __shfl_xor(uB1[r], m);
            uB2[r] += __shfl_xor(uB2[r], m);
            uB3[r] += __shfl_xor(uB3[r], m);
        }
    }
    // gather tangent sums onto q0: pa from q2 (xor32), pb from q3 (xor48)
    float paA0[4], paA1[4], paA2[4], paA3[4], pbA0[4], pbA1[4], pbA2[4], pbA3[4];
    float paB0[4], paB1[4], paB2[4], paB3[4], pbB0[4], pbB1[4], pbB2[4], pbB3[4];
    #pragma unroll
    for (int r = 0; r < 4; ++r) {
        paA0[r] = __shfl_xor(uA0[r], 32);
        paA1[r] = __shfl_xor(uA1[r], 32);
        paA2[r] = __shfl_xor(uA2[r], 32);
        paA3[r] = __shfl_xor(uA3[r], 32);
        pbA0[r] = __shfl_xor(uA0[r], 48);
        pbA1[r] = __shfl_xor(uA1[r], 48);
        pbA2[r] = __shfl_xor(uA2[r], 48);
        pbA3[r] = __shfl_xor(uA3[r], 48);
        paB0[r] = __shfl_xor(uB0[r], 32);
        paB1[r] = __shfl_xor(uB1[r], 32);
        paB2[r] = __shfl_xor(uB2[r], 32);
        paB3[r] = __shfl_xor(uB3[r], 32);
        pbB0[r] = __shfl_xor(uB0[r], 48);
        pbB1[r] = __shfl_xor(uB1[r], 48);
        pbB2[r] = __shfl_xor(uB2[r], 48);
        pbB3[r] = __shfl_xor(uB3[r], 48);
    }

    if (lane == 0) {
        const float bd0 = bd[0], bd1 = bd[1], bo0 = bo[0];
        const int base = blockIdx.x * SB + wave * 8;
        #pragma unroll
        for (int r = 0; r < 4; ++r) {
            if (base + r < n)
                solve_write(x, out, base + r,
                            uA0[r], uA1[r], uA2[r],
                            paA0[r], paA1[r], paA2[r], paA3[r],
                            pbA0[r], pbA1[r], pbA2[r], pbA3[r], bd0, bd1, bo0);
            if (base + 4 + r < n)
                solve_write(x, out, base + 4 + r,
                            uB0[r], uB1[r], uB2[r],
                            paB0[r], paB1[r], paB2[r], paB3[r],
                            pbB0[r], pbB1[r], pbB2[r], pbB3[r], bd0, bd1, bo0);
        }
    }
}

extern "C" void kernel_launch(void* const* d_in, const int* in_sizes, int n_in,
                              void* d_out, int out_size, void* d_ws, size_t ws_size,
                              hipStream_t stream) {
    // dict order: t, x, W0, b0, W1, b1, Wd, bd, Wo, bo, Wv, bv
    const float* x  = (const float*)d_in[1];
    const float* W0 = (const float*)d_in[2];
    const float* b0 = (const float*)d_in[3];
    const float* W1 = (const float*)d_in[4];
    const float* b1 = (const float*)d_in[5];
    const float* Wd = (const float*)d_in[6];
    const float* bd = (const float*)d_in[7];
    const float* Wo = (const float*)d_in[8];
    const float* bo = (const float*)d_in[9];
    const float* Wv = (const float*)d_in[10];
    float* out = (float*)d_out;

    unsigned short* wB = (unsigned short*)d_ws;                         // 256 KB
    float4* w0p = (float4*)((char*)d_ws + 262144);                      // 4 KB
    float4* hwp = (float4*)((char*)d_ws + 262144 + 4096);               // 4 KB

    const int n = in_sizes[1] / 6;

    prep<<<32, 256, 0, stream>>>(W1, W0, Wd, Wo, Wv, wB, w0p, hwp);

    const int grid = (n + SB - 1) / SB;
    lode_mfma<<<grid, NTHREADS, 0, stream>>>(x, w0p, b0, wB, b1, hwp, bd, bo, out, n);
}